// Round 11
// baseline (150.221 us; speedup 1.0000x reference)
//
#include <hip/hip_runtime.h>
#include <stdint.h>
#include <stddef.h>

#define DEVI __device__ __forceinline__

typedef __bf16 bf16x8 __attribute__((ext_vector_type(8)));
typedef float  f32x4  __attribute__((ext_vector_type(4)));
typedef float  f32x16 __attribute__((ext_vector_type(16)));
typedef unsigned short u16;
typedef uint32_t u32;
typedef u16 u16x8 __attribute__((ext_vector_type(8)));
typedef u16 u16x4 __attribute__((ext_vector_type(4)));
typedef u32 u32x2 __attribute__((ext_vector_type(2)));
typedef u32 u32x4 __attribute__((ext_vector_type(4)));

typedef __attribute__((address_space(1))) void as1_void;
typedef __attribute__((address_space(3))) void as3_void;

static constexpr float SC = 0.18033688011112042f;  // (1/8) * log2(e)

DEVI u16 f2bf(float f) {
  uint32_t u = __builtin_bit_cast(uint32_t, f);
  u += 0x7fffu + ((u >> 16) & 1u);
  return (u16)(u >> 16);
}

DEVI void gload_lds16(const void* g, void* l) {
  __builtin_amdgcn_global_load_lds((as1_void*)(void*)g, (as3_void*)l, 16, 0, 0);
}

#if __has_builtin(__builtin_amdgcn_exp2f)
DEVI float fast_exp2(float x) { return __builtin_amdgcn_exp2f(x); }
#else
DEVI float fast_exp2(float x) { return exp2f(x); }
#endif

DEVI u32 cvtpk(float lo, float hi) {
  u32 r;
  asm("v_cvt_pk_bf16_f32 %0, %1, %2" : "=v"(r) : "v"(lo), "v"(hi));
  return r;
}
DEVI void plswap(u32& a, u32& b) {
  asm("v_permlane32_swap_b32 %0, %1" : "+v"(a), "+v"(b));
}

// ---------------- elementwise fp32 -> bf16 ----------------
__global__ __launch_bounds__(256) void k_cvt(const float* __restrict__ in,
                                             u16* __restrict__ out, int n) {
  int i = (blockIdx.x * 256 + threadIdx.x) * 4;
  if (i >= n) return;
  const float4 v = *(const float4*)(in + i);
  u16x4 o = { f2bf(v.x), f2bf(v.y), f2bf(v.z), f2bf(v.w) };
  *(u16x4*)(out + i) = o;
}

// ------------- transpose + convert: in fp32 [R][C] -> out bf16 [C][R] -------------
__global__ __launch_bounds__(256) void k_tcvt(const float* __restrict__ in,
                                              u16* __restrict__ out, int R, int C) {
  __shared__ float tile[32][33];
  const int c0 = blockIdx.x * 32, r0 = blockIdx.y * 32;
  const int tx = threadIdx.x, ty = threadIdx.y;
#pragma unroll
  for (int i = ty; i < 32; i += 8)
    tile[i][tx] = in[(size_t)(r0 + i) * C + (c0 + tx)];
  __syncthreads();
#pragma unroll
  for (int i = ty; i < 32; i += 8)
    out[(size_t)(c0 + i) * R + (r0 + tx)] = f2bf(tile[tx][i]);
}

// ---------------- GEMM: C[M][N] = A[M][K] * Bt[N][K]^T  (bf16 in, fp32 acc) ----------------
// Tri-buffered LDS + counted s_waitcnt vmcnt(4) + raw s_barrier (T3/T4) +
// T1 XCD-chunked bid remap.
// EPI 0: qkv epilogue -> q,k bf16 [B,H,S,d]; v -> fp32 present + bf16 vT [B,H,d,S]
// EPI 1: proj epilogue (fp32 out + bias)
template <int EPI>
__global__ __launch_bounds__(256) void k_gemm(
    const u16* __restrict__ A, const u16* __restrict__ Bt,
    const float* __restrict__ bias,
    u16* __restrict__ wq, u16* __restrict__ wk, u16* __restrict__ vt,
    float* __restrict__ pk, float* __restrict__ pv, float* __restrict__ of) {
  constexpr int K = 1024;
  constexpr int NT = K / 32;
  __shared__ __align__(16) u16 Ash[3][128 * 32];
  __shared__ __align__(16) u16 Bsh[3][128 * 32];
  const int tid = threadIdx.x;
  const int lane = tid & 63, wid = tid >> 6;
  const int wm = wid >> 1, wn = wid & 1;
  const int lr = lane & 15, lg = lane >> 4;

  // T1: XCD-chunked remap (nwg % 8 == 0 in both uses -> bijective)
  const int nwgx = gridDim.x;
  const int nwg = nwgx * gridDim.y;
  int lbid = blockIdx.y * nwgx + blockIdx.x;
  lbid = (lbid & 7) * (nwg >> 3) + (lbid >> 3);
  const int m0 = (lbid / nwgx) * 128, n0 = (lbid % nwgx) * 128;

  const int c = wid * 64 + lane;  // 16B chunk id, 0..255
  const u16* Ag1 = A + (size_t)(m0 + (c >> 2)) * K + (c & 3) * 8;
  const u16* Ag2 = A + (size_t)(m0 + 64 + (c >> 2)) * K + (c & 3) * 8;
  const u16* Bg1 = Bt + (size_t)(n0 + (c >> 2)) * K + (c & 3) * 8;
  const u16* Bg2 = Bt + (size_t)(n0 + 64 + (c >> 2)) * K + (c & 3) * 8;

  f32x4 acc[4][4];
#pragma unroll
  for (int i = 0; i < 4; ++i)
#pragma unroll
    for (int j = 0; j < 4; ++j) acc[i][j] = (f32x4)0.0f;

#define STAGE(sel, kk)                                        \
  {                                                           \
    gload_lds16(Ag1 + (kk), &Ash[sel][wid * 512]);            \
    gload_lds16(Ag2 + (kk), &Ash[sel][2048 + wid * 512]);     \
    gload_lds16(Bg1 + (kk), &Bsh[sel][wid * 512]);            \
    gload_lds16(Bg2 + (kk), &Bsh[sel][2048 + wid * 512]);     \
  }

  STAGE(0, 0)
  STAGE(1, 32)
  asm volatile("s_waitcnt vmcnt(4)" ::: "memory");
  __builtin_amdgcn_sched_barrier(0);
  __builtin_amdgcn_s_barrier();
  __builtin_amdgcn_sched_barrier(0);

  int cur = 0;
  for (int j = 0; j < NT; ++j) {
    const bool pf = (j + 2 < NT);
    int nb = cur + 2; if (nb >= 3) nb -= 3;
    if (pf) STAGE(nb, (j + 2) * 32)
    bf16x8 af[4], bfr[4];
#pragma unroll
    for (int f = 0; f < 4; ++f) {
      af[f]  = *(const bf16x8*)&Ash[cur][(wm * 64 + f * 16 + lr) * 32 + lg * 8];
      bfr[f] = *(const bf16x8*)&Bsh[cur][(wn * 64 + f * 16 + lr) * 32 + lg * 8];
    }
    __builtin_amdgcn_s_setprio(1);
#pragma unroll
    for (int i = 0; i < 4; ++i)
#pragma unroll
      for (int jj = 0; jj < 4; ++jj)
        acc[i][jj] = __builtin_amdgcn_mfma_f32_16x16x32_bf16(af[i], bfr[jj], acc[i][jj], 0, 0, 0);
    __builtin_amdgcn_s_setprio(0);
    // counted wait: keep tile j+2's 4 loads in flight across the barrier
    if (pf) asm volatile("s_waitcnt vmcnt(4)" ::: "memory");
    else    asm volatile("s_waitcnt vmcnt(0)" ::: "memory");
    __builtin_amdgcn_sched_barrier(0);
    __builtin_amdgcn_s_barrier();
    __builtin_amdgcn_sched_barrier(0);
    cur = (cur + 1 == 3) ? 0 : cur + 1;
  }
#undef STAGE

  if constexpr (EPI == 0) {
#pragma unroll
    for (int j = 0; j < 4; ++j) {
      const int n = n0 + wn * 64 + j * 16 + lr;
      const float bv = bias[n];
      const int sec = n >> 10;
      const int nn = n & 1023;
      const int h = nn >> 6, dd = nn & 63;
#pragma unroll
      for (int i = 0; i < 4; ++i) {
        const int mb = m0 + wm * 64 + i * 16 + lg * 4;
        const int bb = mb >> 11, ss = mb & 2047;
        const size_t ib = (size_t)(bb * 16 + h) * 131072 + (size_t)ss * 64 + dd;
        if (sec == 0) {
#pragma unroll
          for (int r = 0; r < 4; ++r)
            wq[ib + (size_t)r * 64] = f2bf(acc[i][j][r] + bv);
        } else if (sec == 1) {
#pragma unroll
          for (int r = 0; r < 4; ++r) {
            const float v = acc[i][j][r] + bv;
            wk[ib + (size_t)r * 64] = f2bf(v);
            pk[ib + (size_t)r * 64] = v;
          }
        } else {
          u16x4 vv;
#pragma unroll
          for (int r = 0; r < 4; ++r) {
            const float v = acc[i][j][r] + bv;
            pv[ib + (size_t)r * 64] = v;
            vv[r] = f2bf(v);
          }
          // direct vT scatter (fire-and-forget stores; r9 showed removing it
          // bought no gemm time, so produce vT here and skip a transpose pass)
          *(u16x4*)(vt + ((size_t)(bb * 16 + h) * 64 + dd) * 2048 + ss) = vv;
        }
      }
    }
  } else {
#pragma unroll
    for (int j = 0; j < 4; ++j) {
      const int n = n0 + wn * 64 + j * 16 + lr;
      const float bv = bias[n];
#pragma unroll
      for (int i = 0; i < 4; ++i) {
        const int mb = m0 + wm * 64 + i * 16 + lg * 4;
#pragma unroll
        for (int r = 0; r < 4; ++r)
          of[(size_t)(mb + r) * 1024 + n] = acc[i][j][r] + bv;
      }
    }
  }
}

// ---------------- causal flash attention: double-buffered LDS K/V ----------------
// 1024 blocks x 128 thr (2 waves). bh = bid&31 (XCD-pinned).
// Balanced 4-class qt mapping: each CU-class's 4 blocks total 66 KV-iters.
// Double-buffered LDS (32 KB) -> 5 blocks/CU (160 KiB exactly) = 10 waves/CU.
// Distance-1 prefetch; per-iter compute (~500 cyc) covers the load latency, so
// the __syncthreads drain is cheap (measured: r8 dbuf == r10 tri within 3%).
__global__ __launch_bounds__(128) void k_attn(const u16* __restrict__ Q,
                                              const u16* __restrict__ Kp,
                                              const u16* __restrict__ VT,
                                              u16* __restrict__ AO) {
  __shared__ __align__(16) u16 Ksh[2][4096];  // [kpos 64][d 64], swizzled
  __shared__ __align__(16) u16 Vsh[2][4096];  // [d 64][kpos 64], swizzled

  const int tid = threadIdx.x;
  const int lane = tid & 63, w = tid >> 6;    // w in {0,1}
  const int l31 = lane & 31, hi = lane >> 5;
  const int bid = blockIdx.x;
  const int bh = bid & 31;                    // bh%8 == bid%8 -> XCD-pinned
  const int j4 = bid >> 8;                    // work class 0..3
  const int g  = (bid >> 5) & 7;
  const int qt = (j4 == 0) ? (31 - g) : (j4 == 1) ? g : (j4 == 2) ? (23 - g) : (8 + g);
  const int b = bh >> 4, h = bh & 15;
  const size_t hb = (size_t)bh * (2048 * 64);

  const int T = qt + 1;                       // KV tiles (diag = T-1 for both waves)
  const int qb = qt * 64 + w * 32;            // this wave's 32 q-rows

  // staging source (pre-swizzled): (row & 7) == (lane>>3) regardless of chunk
  const int srow = w * 32 + (lane >> 3);
  const int sslot = (lane & 7) ^ (lane >> 3);
  const u16* Kg = Kp + hb + (size_t)srow * 64 + sslot * 8;
  const u16* Vg = VT + hb + (size_t)srow * 2048 + sslot * 8;

#define STAGEA(sel, jt)                                                       \
  {                                                                           \
    gload_lds16(Kg + (size_t)(jt) * 4096,          &Ksh[sel][w * 2048]);      \
    gload_lds16(Kg + (size_t)(jt) * 4096 + 512,    &Ksh[sel][w * 2048 + 512]);\
    gload_lds16(Kg + (size_t)(jt) * 4096 + 1024,   &Ksh[sel][w * 2048 + 1024]);\
    gload_lds16(Kg + (size_t)(jt) * 4096 + 1536,   &Ksh[sel][w * 2048 + 1536]);\
    gload_lds16(Vg + (size_t)(jt) * 64,            &Vsh[sel][w * 2048]);      \
    gload_lds16(Vg + (size_t)(jt) * 64 + 16384,    &Vsh[sel][w * 2048 + 512]);\
    gload_lds16(Vg + (size_t)(jt) * 64 + 32768,    &Vsh[sel][w * 2048 + 1024]);\
    gload_lds16(Vg + (size_t)(jt) * 64 + 49152,    &Vsh[sel][w * 2048 + 1536]);\
  }

  // Q fragments (held in registers for the whole block)
  const u16* Qp = Q + hb + (size_t)(qb + l31) * 64 + hi * 8;
  const bf16x8 qf0 = *(const bf16x8*)(Qp);
  const bf16x8 qf1 = *(const bf16x8*)(Qp + 16);
  const bf16x8 qf2 = *(const bf16x8*)(Qp + 32);
  const bf16x8 qf3 = *(const bf16x8*)(Qp + 48);

  f32x16 o0 = (f32x16)0.0f, o1 = (f32x16)0.0f;
  float mrun = -1e30f, lrun = 0.0f;

  const int xr = l31 & 7;  // read-side swizzle key

  STAGEA(0, 0)
  __syncthreads();

  int sel = 0;
  for (int jt = 0; jt < T; ++jt) {
    if (jt + 1 < T) STAGEA(sel ^ 1, jt + 1)
    const u16* Kb = Ksh[sel];
    const u16* Vb = Vsh[sel];
    // K fragments: row = s*32+l31, want slot 2c+hi -> read slot ^ (row&7)
    bf16x8 kf[2][4];
#pragma unroll
    for (int s = 0; s < 2; ++s)
#pragma unroll
      for (int c = 0; c < 4; ++c)
        kf[s][c] = *(const bf16x8*)&Kb[(s * 32 + l31) * 64 + (((2 * c + hi) ^ xr) * 8)];

    // S^T[kpos][q] = K . Q^T
    f32x16 s0 = (f32x16)0.0f, s1 = (f32x16)0.0f;
    __builtin_amdgcn_s_setprio(1);
    s0 = __builtin_amdgcn_mfma_f32_32x32x16_bf16(kf[0][0], qf0, s0, 0, 0, 0);
    s1 = __builtin_amdgcn_mfma_f32_32x32x16_bf16(kf[1][0], qf0, s1, 0, 0, 0);
    s0 = __builtin_amdgcn_mfma_f32_32x32x16_bf16(kf[0][1], qf1, s0, 0, 0, 0);
    s1 = __builtin_amdgcn_mfma_f32_32x32x16_bf16(kf[1][1], qf1, s1, 0, 0, 0);
    s0 = __builtin_amdgcn_mfma_f32_32x32x16_bf16(kf[0][2], qf2, s0, 0, 0, 0);
    s1 = __builtin_amdgcn_mfma_f32_32x32x16_bf16(kf[1][2], qf2, s1, 0, 0, 0);
    s0 = __builtin_amdgcn_mfma_f32_32x32x16_bf16(kf[0][3], qf3, s0, 0, 0, 0);
    s1 = __builtin_amdgcn_mfma_f32_32x32x16_bf16(kf[1][3], qf3, s1, 0, 0, 0);
    __builtin_amdgcn_s_setprio(0);

    // causal mask (diagonal tile only; qrel = w*32 + l31)
    if (jt == T - 1) {
      const int qrel = w * 32 + l31;
      const int h4 = hi * 4;
#pragma unroll
      for (int r = 0; r < 16; ++r) {
        const int kp = (r & 3) + ((r >> 2) << 3) + h4;
        s0[r] = (kp <= qrel) ? s0[r] : -1e30f;
        s1[r] = (kp + 32 <= qrel) ? s1[r] : -1e30f;
      }
    }

    // ---- in-register online softmax (lane pair (l31,hi) = one q-row) ----
    float t8[8];
#pragma unroll
    for (int r = 0; r < 8; ++r)
      t8[r] = fmaxf(fmaxf(s0[r], s0[r + 8]), fmaxf(s1[r], s1[r + 8]));
    float tm = fmaxf(fmaxf(fmaxf(t8[0], t8[1]), fmaxf(t8[2], t8[3])),
                     fmaxf(fmaxf(t8[4], t8[5]), fmaxf(t8[6], t8[7])));
    tm = fmaxf(tm, __shfl_xor(tm, 32));
    if (!__all(tm <= mrun)) {
      const float mnew = fmaxf(mrun, tm);
      const float al = fast_exp2((mrun - mnew) * SC);
      mrun = mnew;
      lrun *= al;
#pragma unroll
      for (int r = 0; r < 16; ++r) { o0[r] *= al; o1[r] *= al; }
    }
    const float nb2 = -mrun * SC;
#pragma unroll
    for (int r = 0; r < 16; ++r) {
      s0[r] = fast_exp2(fmaf(s0[r], SC, nb2));
      s1[r] = fast_exp2(fmaf(s1[r], SC, nb2));
    }
    float u8[8];
#pragma unroll
    for (int r = 0; r < 8; ++r)
      u8[r] = (s0[r] + s0[r + 8]) + (s1[r] + s1[r + 8]);
    lrun += ((u8[0] + u8[1]) + (u8[2] + u8[3])) + ((u8[4] + u8[5]) + (u8[6] + u8[7]));

    // ---- pack P to bf16 B-fragments (cvt_pk + permlane32_swap, T12) ----
    bf16x8 pb0, pb1, pb2, pb3;
#define PACK_CHUNK(sv, bb, dst)                                   \
    {                                                             \
      u32 a0 = cvtpk(sv[bb + 0], sv[bb + 1]);                     \
      u32 a1 = cvtpk(sv[bb + 2], sv[bb + 3]);                     \
      u32 a2 = cvtpk(sv[bb + 4], sv[bb + 5]);                     \
      u32 a3 = cvtpk(sv[bb + 6], sv[bb + 7]);                     \
      plswap(a0, a2);                                             \
      plswap(a1, a3);                                             \
      u32x4 fv = {a0, a1, a2, a3};                                \
      dst = __builtin_bit_cast(bf16x8, fv);                       \
    }
    PACK_CHUNK(s0, 0, pb0)
    PACK_CHUNK(s0, 8, pb1)
    PACK_CHUNK(s1, 0, pb2)
    PACK_CHUNK(s1, 8, pb3)
#undef PACK_CHUNK

    // V^T fragments: row = mt*32+l31 (d), want slot 2c+hi -> read slot ^ (row&7)
    bf16x8 vf[2][4];
#pragma unroll
    for (int mt = 0; mt < 2; ++mt)
#pragma unroll
      for (int c = 0; c < 4; ++c)
        vf[mt][c] = *(const bf16x8*)&Vb[(mt * 32 + l31) * 64 + (((2 * c + hi) ^ xr) * 8)];

    // ---- O^T[d][q] += V^T . P^T ----
    __builtin_amdgcn_s_setprio(1);
    o0 = __builtin_amdgcn_mfma_f32_32x32x16_bf16(vf[0][0], pb0, o0, 0, 0, 0);
    o1 = __builtin_amdgcn_mfma_f32_32x32x16_bf16(vf[1][0], pb0, o1, 0, 0, 0);
    o0 = __builtin_amdgcn_mfma_f32_32x32x16_bf16(vf[0][1], pb1, o0, 0, 0, 0);
    o1 = __builtin_amdgcn_mfma_f32_32x32x16_bf16(vf[1][1], pb1, o1, 0, 0, 0);
    o0 = __builtin_amdgcn_mfma_f32_32x32x16_bf16(vf[0][2], pb2, o0, 0, 0, 0);
    o1 = __builtin_amdgcn_mfma_f32_32x32x16_bf16(vf[1][2], pb2, o1, 0, 0, 0);
    o0 = __builtin_amdgcn_mfma_f32_32x32x16_bf16(vf[0][3], pb3, o0, 0, 0, 0);
    o1 = __builtin_amdgcn_mfma_f32_32x32x16_bf16(vf[1][3], pb3, o1, 0, 0, 0);
    __builtin_amdgcn_s_setprio(0);

    __syncthreads();  // drains staged loads + protects buffer reuse
    sel ^= 1;
  }
#undef STAGEA

  // ---- epilogue: combine partner row-sums, normalize, store bf16 (per wave) ----
  const float lt = lrun + __shfl_xor(lrun, 32);
  const float inv = 1.0f / lt;
  u16* aorow = AO + (size_t)(b * 2048 + qb + l31) * 1024 + h * 64 + hi * 4;
#pragma unroll
  for (int g2 = 0; g2 < 4; ++g2) {
    u32 w0 = cvtpk(o0[4 * g2 + 0] * inv, o0[4 * g2 + 1] * inv);
    u32 w1 = cvtpk(o0[4 * g2 + 2] * inv, o0[4 * g2 + 3] * inv);
    u32x2 ww = {w0, w1};
    *(u32x2*)(aorow + g2 * 8) = ww;
  }
#pragma unroll
  for (int g2 = 0; g2 < 4; ++g2) {
    u32 w0 = cvtpk(o1[4 * g2 + 0] * inv, o1[4 * g2 + 1] * inv);
    u32 w1 = cvtpk(o1[4 * g2 + 2] * inv, o1[4 * g2 + 3] * inv);
    u32x2 ww = {w0, w1};
    *(u32x2*)(aorow + 32 + g2 * 8) = ww;
  }
}

extern "C" void kernel_launch(void* const* d_in, const int* in_sizes, int n_in,
                              void* d_out, int out_size, void* d_ws, size_t ws_size,
                              hipStream_t stream) {
  const float* x      = (const float*)d_in[0];
  const float* w_attn = (const float*)d_in[1];
  const float* b_attn = (const float*)d_in[2];
  const float* w_proj = (const float*)d_in[3];
  const float* b_proj = (const float*)d_in[4];
  float* out = (float*)d_out;

  char* ws = (char*)d_ws;
  u16* x_bf  = (u16*)(ws);                    // [4096][1024] bf16   (8 MB)
  u16* wat_t = (u16*)(ws + 8388608);          // [3072][1024] bf16   (6 MB)
  u16* wpj_t = (u16*)(ws + 14680064);         // [1024][1024] bf16   (2 MB)
  u16* q_ws  = (u16*)(ws + 16777216);         // [B,H,S,d] bf16      (8 MB)
  u16* k_ws  = (u16*)(ws + 25165824);         // [B,H,S,d] bf16      (8 MB)
  u16* vT_ws = (u16*)(ws + 33554432);         // [B,H,d,S] bf16      (8 MB)
  u16* a_ws  = (u16*)(ws + 41943040);         // [B,S,nx]  bf16      (8 MB)

  k_cvt<<<4096, 256, 0, stream>>>(x, x_bf, 4194304);
  k_tcvt<<<dim3(96, 32), dim3(32, 8), 0, stream>>>(w_attn, wat_t, 1024, 3072);
  k_tcvt<<<dim3(32, 32), dim3(32, 8), 0, stream>>>(w_proj, wpj_t, 1024, 1024);

  k_gemm<0><<<dim3(24, 32), 256, 0, stream>>>(x_bf, wat_t, b_attn,
                                              q_ws, k_ws, vT_ws,
                                              out + 4194304, out + 8388608, nullptr);

  k_attn<<<dim3(1024), 128, 0, stream>>>(q_ws, k_ws, vT_ws, a_ws);

  k_gemm<1><<<dim3(8, 32), 256, 0, stream>>>(a_ws, wpj_t, b_proj,
                                             nullptr, nullptr, nullptr,
                                             nullptr, nullptr, out);
}

// Round 12
// 137.958 us; speedup vs baseline: 1.0889x; 1.0889x over previous
//
#include <hip/hip_runtime.h>
#include <stdint.h>
#include <stddef.h>

#define DEVI __device__ __forceinline__

typedef __bf16 bf16x8 __attribute__((ext_vector_type(8)));
typedef float  f32x4  __attribute__((ext_vector_type(4)));
typedef float  f32x16 __attribute__((ext_vector_type(16)));
typedef unsigned short u16;
typedef uint32_t u32;
typedef u16 u16x8 __attribute__((ext_vector_type(8)));
typedef u16 u16x4 __attribute__((ext_vector_type(4)));
typedef u32 u32x2 __attribute__((ext_vector_type(2)));
typedef u32 u32x4 __attribute__((ext_vector_type(4)));

typedef __attribute__((address_space(1))) void as1_void;
typedef __attribute__((address_space(3))) void as3_void;

static constexpr float SC = 0.18033688011112042f;  // (1/8) * log2(e)

DEVI u16 f2bf(float f) {
  uint32_t u = __builtin_bit_cast(uint32_t, f);
  u += 0x7fffu + ((u >> 16) & 1u);
  return (u16)(u >> 16);
}

DEVI void gload_lds16(const void* g, void* l) {
  __builtin_amdgcn_global_load_lds((as1_void*)(void*)g, (as3_void*)l, 16, 0, 0);
}

#if __has_builtin(__builtin_amdgcn_exp2f)
DEVI float fast_exp2(float x) { return __builtin_amdgcn_exp2f(x); }
#else
DEVI float fast_exp2(float x) { return exp2f(x); }
#endif

DEVI u32 cvtpk(float lo, float hi) {
  u32 r;
  asm("v_cvt_pk_bf16_f32 %0, %1, %2" : "=v"(r) : "v"(lo), "v"(hi));
  return r;
}
DEVI void plswap(u32& a, u32& b) {
  asm("v_permlane32_swap_b32 %0, %1" : "+v"(a), "+v"(b));
}

// ---------------- elementwise fp32 -> bf16 ----------------
__global__ __launch_bounds__(256) void k_cvt(const float* __restrict__ in,
                                             u16* __restrict__ out, int n) {
  int i = (blockIdx.x * 256 + threadIdx.x) * 4;
  if (i >= n) return;
  const float4 v = *(const float4*)(in + i);
  u16x4 o = { f2bf(v.x), f2bf(v.y), f2bf(v.z), f2bf(v.w) };
  *(u16x4*)(out + i) = o;
}

// ------------- transpose + convert: in fp32 [R][C] -> out bf16 [C][R] -------------
__global__ __launch_bounds__(256) void k_tcvt(const float* __restrict__ in,
                                              u16* __restrict__ out, int R, int C) {
  __shared__ float tile[32][33];
  const int c0 = blockIdx.x * 32, r0 = blockIdx.y * 32;
  const int tx = threadIdx.x, ty = threadIdx.y;
#pragma unroll
  for (int i = ty; i < 32; i += 8)
    tile[i][tx] = in[(size_t)(r0 + i) * C + (c0 + tx)];
  __syncthreads();
#pragma unroll
  for (int i = ty; i < 32; i += 8)
    out[(size_t)(c0 + i) * R + (r0 + tx)] = f2bf(tile[tx][i]);
}

// ------------- per-head bf16 transpose: [S 2048][d 64] -> [d 64][S 2048] -------------
__global__ __launch_bounds__(256) void k_vt(const u16* __restrict__ in,
                                            u16* __restrict__ out) {
  __shared__ u16 tile[64][72];
  const int tid = threadIdx.x;
  const int s0 = blockIdx.x * 64;
  const int bh = blockIdx.y;
  const size_t ib = (size_t)bh * 131072;
#pragma unroll
  for (int it = 0; it < 2; ++it) {
    const int r = (tid >> 3) + it * 32;
    const int c8 = (tid & 7) * 8;
    u16x8 v = *(const u16x8*)(in + ib + (size_t)(s0 + r) * 64 + c8);
    *(u16x8*)&tile[r][c8] = v;
  }
  __syncthreads();
#pragma unroll
  for (int it = 0; it < 2; ++it) {
    const int d = (tid >> 3) + it * 32;
    const int s8 = (tid & 7) * 8;
    u16x8 v;
#pragma unroll
    for (int jj = 0; jj < 8; ++jj) v[jj] = tile[s8 + jj][d];
    *(u16x8*)(out + ib + (size_t)d * 2048 + s0 + s8) = v;
  }
}

// ---------------- GEMM: C[M][N] = A[M][K] * Bt[N][K]^T  (bf16 in, fp32 acc) ----------------
// Tri-buffered LDS + counted s_waitcnt vmcnt(4) + raw s_barrier (T3/T4) +
// T1 XCD-chunked bid remap. Clean coalesced epilogue (NO vT scatter — r11
// showed it costs VGPR 64->108 and +17 us in this pipelined structure).
// EPI 0: qkv epilogue -> q,k,v bf16 [B,H,S,d] (coalesced) + present fp32
// EPI 1: proj epilogue (fp32 out + bias)
template <int EPI>
__global__ __launch_bounds__(256) void k_gemm(
    const u16* __restrict__ A, const u16* __restrict__ Bt,
    const float* __restrict__ bias,
    u16* __restrict__ wq, u16* __restrict__ wk, u16* __restrict__ wv,
    float* __restrict__ pk, float* __restrict__ pv, float* __restrict__ of) {
  constexpr int K = 1024;
  constexpr int NT = K / 32;
  __shared__ __align__(16) u16 Ash[3][128 * 32];
  __shared__ __align__(16) u16 Bsh[3][128 * 32];
  const int tid = threadIdx.x;
  const int lane = tid & 63, wid = tid >> 6;
  const int wm = wid >> 1, wn = wid & 1;
  const int lr = lane & 15, lg = lane >> 4;

  // T1: XCD-chunked remap (nwg % 8 == 0 in both uses -> bijective)
  const int nwgx = gridDim.x;
  const int nwg = nwgx * gridDim.y;
  int lbid = blockIdx.y * nwgx + blockIdx.x;
  lbid = (lbid & 7) * (nwg >> 3) + (lbid >> 3);
  const int m0 = (lbid / nwgx) * 128, n0 = (lbid % nwgx) * 128;

  const int c = wid * 64 + lane;  // 16B chunk id, 0..255
  const u16* Ag1 = A + (size_t)(m0 + (c >> 2)) * K + (c & 3) * 8;
  const u16* Ag2 = A + (size_t)(m0 + 64 + (c >> 2)) * K + (c & 3) * 8;
  const u16* Bg1 = Bt + (size_t)(n0 + (c >> 2)) * K + (c & 3) * 8;
  const u16* Bg2 = Bt + (size_t)(n0 + 64 + (c >> 2)) * K + (c & 3) * 8;

  f32x4 acc[4][4];
#pragma unroll
  for (int i = 0; i < 4; ++i)
#pragma unroll
    for (int j = 0; j < 4; ++j) acc[i][j] = (f32x4)0.0f;

#define STAGE(sel, kk)                                        \
  {                                                           \
    gload_lds16(Ag1 + (kk), &Ash[sel][wid * 512]);            \
    gload_lds16(Ag2 + (kk), &Ash[sel][2048 + wid * 512]);     \
    gload_lds16(Bg1 + (kk), &Bsh[sel][wid * 512]);            \
    gload_lds16(Bg2 + (kk), &Bsh[sel][2048 + wid * 512]);     \
  }

  STAGE(0, 0)
  STAGE(1, 32)
  asm volatile("s_waitcnt vmcnt(4)" ::: "memory");
  __builtin_amdgcn_sched_barrier(0);
  __builtin_amdgcn_s_barrier();
  __builtin_amdgcn_sched_barrier(0);

  int cur = 0;
  for (int j = 0; j < NT; ++j) {
    const bool pf = (j + 2 < NT);
    int nb = cur + 2; if (nb >= 3) nb -= 3;
    if (pf) STAGE(nb, (j + 2) * 32)
    bf16x8 af[4], bfr[4];
#pragma unroll
    for (int f = 0; f < 4; ++f) {
      af[f]  = *(const bf16x8*)&Ash[cur][(wm * 64 + f * 16 + lr) * 32 + lg * 8];
      bfr[f] = *(const bf16x8*)&Bsh[cur][(wn * 64 + f * 16 + lr) * 32 + lg * 8];
    }
    __builtin_amdgcn_s_setprio(1);
#pragma unroll
    for (int i = 0; i < 4; ++i)
#pragma unroll
      for (int jj = 0; jj < 4; ++jj)
        acc[i][jj] = __builtin_amdgcn_mfma_f32_16x16x32_bf16(af[i], bfr[jj], acc[i][jj], 0, 0, 0);
    __builtin_amdgcn_s_setprio(0);
    // counted wait: keep tile j+2's 4 loads in flight across the barrier
    if (pf) asm volatile("s_waitcnt vmcnt(4)" ::: "memory");
    else    asm volatile("s_waitcnt vmcnt(0)" ::: "memory");
    __builtin_amdgcn_sched_barrier(0);
    __builtin_amdgcn_s_barrier();
    __builtin_amdgcn_sched_barrier(0);
    cur = (cur + 1 == 3) ? 0 : cur + 1;
  }
#undef STAGE

  if constexpr (EPI == 0) {
#pragma unroll
    for (int j = 0; j < 4; ++j) {
      const int n = n0 + wn * 64 + j * 16 + lr;
      const float bv = bias[n];
      const int sec = n >> 10;
      const int nn = n & 1023;
      const int h = nn >> 6, dd = nn & 63;
#pragma unroll
      for (int i = 0; i < 4; ++i) {
        const int mb = m0 + wm * 64 + i * 16 + lg * 4;
        const int bb = mb >> 11, ss = mb & 2047;
        const size_t ib = (size_t)(bb * 16 + h) * 131072 + (size_t)ss * 64 + dd;
        if (sec == 0) {
#pragma unroll
          for (int r = 0; r < 4; ++r)
            wq[ib + (size_t)r * 64] = f2bf(acc[i][j][r] + bv);
        } else if (sec == 1) {
#pragma unroll
          for (int r = 0; r < 4; ++r) {
            const float v = acc[i][j][r] + bv;
            wk[ib + (size_t)r * 64] = f2bf(v);
            pk[ib + (size_t)r * 64] = v;
          }
        } else {
#pragma unroll
          for (int r = 0; r < 4; ++r) {
            const float v = acc[i][j][r] + bv;
            wv[ib + (size_t)r * 64] = f2bf(v);
            pv[ib + (size_t)r * 64] = v;
          }
        }
      }
    }
  } else {
#pragma unroll
    for (int j = 0; j < 4; ++j) {
      const int n = n0 + wn * 64 + j * 16 + lr;
      const float bv = bias[n];
#pragma unroll
      for (int i = 0; i < 4; ++i) {
        const int mb = m0 + wm * 64 + i * 16 + lg * 4;
#pragma unroll
        for (int r = 0; r < 4; ++r)
          of[(size_t)(mb + r) * 1024 + n] = acc[i][j][r] + bv;
      }
    }
  }
}

// ---------------- causal flash attention: double-buffered LDS K/V ----------------
// 1024 blocks x 128 thr (2 waves). bh = bid&31 (XCD-pinned).
// Balanced 4-class qt mapping: each CU-class's 4 blocks total 66 KV-iters.
// Double-buffered LDS (32 KB) -> 5 blocks/CU (160 KiB exactly) = 10 waves/CU.
__global__ __launch_bounds__(128) void k_attn(const u16* __restrict__ Q,
                                              const u16* __restrict__ Kp,
                                              const u16* __restrict__ VT,
                                              u16* __restrict__ AO) {
  __shared__ __align__(16) u16 Ksh[2][4096];  // [kpos 64][d 64], swizzled
  __shared__ __align__(16) u16 Vsh[2][4096];  // [d 64][kpos 64], swizzled

  const int tid = threadIdx.x;
  const int lane = tid & 63, w = tid >> 6;    // w in {0,1}
  const int l31 = lane & 31, hi = lane >> 5;
  const int bid = blockIdx.x;
  const int bh = bid & 31;                    // bh%8 == bid%8 -> XCD-pinned
  const int j4 = bid >> 8;                    // work class 0..3
  const int g  = (bid >> 5) & 7;
  const int qt = (j4 == 0) ? (31 - g) : (j4 == 1) ? g : (j4 == 2) ? (23 - g) : (8 + g);
  const int b = bh >> 4, h = bh & 15;
  const size_t hb = (size_t)bh * (2048 * 64);

  const int T = qt + 1;                       // KV tiles (diag = T-1 for both waves)
  const int qb = qt * 64 + w * 32;            // this wave's 32 q-rows

  // staging source (pre-swizzled): (row & 7) == (lane>>3) regardless of chunk
  const int srow = w * 32 + (lane >> 3);
  const int sslot = (lane & 7) ^ (lane >> 3);
  const u16* Kg = Kp + hb + (size_t)srow * 64 + sslot * 8;
  const u16* Vg = VT + hb + (size_t)srow * 2048 + sslot * 8;

#define STAGEA(sel, jt)                                                       \
  {                                                                           \
    gload_lds16(Kg + (size_t)(jt) * 4096,          &Ksh[sel][w * 2048]);      \
    gload_lds16(Kg + (size_t)(jt) * 4096 + 512,    &Ksh[sel][w * 2048 + 512]);\
    gload_lds16(Kg + (size_t)(jt) * 4096 + 1024,   &Ksh[sel][w * 2048 + 1024]);\
    gload_lds16(Kg + (size_t)(jt) * 4096 + 1536,   &Ksh[sel][w * 2048 + 1536]);\
    gload_lds16(Vg + (size_t)(jt) * 64,            &Vsh[sel][w * 2048]);      \
    gload_lds16(Vg + (size_t)(jt) * 64 + 16384,    &Vsh[sel][w * 2048 + 512]);\
    gload_lds16(Vg + (size_t)(jt) * 64 + 32768,    &Vsh[sel][w * 2048 + 1024]);\
    gload_lds16(Vg + (size_t)(jt) * 64 + 49152,    &Vsh[sel][w * 2048 + 1536]);\
  }

  // Q fragments (held in registers for the whole block)
  const u16* Qp = Q + hb + (size_t)(qb + l31) * 64 + hi * 8;
  const bf16x8 qf0 = *(const bf16x8*)(Qp);
  const bf16x8 qf1 = *(const bf16x8*)(Qp + 16);
  const bf16x8 qf2 = *(const bf16x8*)(Qp + 32);
  const bf16x8 qf3 = *(const bf16x8*)(Qp + 48);

  f32x16 o0 = (f32x16)0.0f, o1 = (f32x16)0.0f;
  float mrun = -1e30f, lrun = 0.0f;

  const int xr = l31 & 7;  // read-side swizzle key

  STAGEA(0, 0)
  __syncthreads();

  int sel = 0;
  for (int jt = 0; jt < T; ++jt) {
    if (jt + 1 < T) STAGEA(sel ^ 1, jt + 1)
    const u16* Kb = Ksh[sel];
    const u16* Vb = Vsh[sel];
    // K fragments: row = s*32+l31, want slot 2c+hi -> read slot ^ (row&7)
    bf16x8 kf[2][4];
#pragma unroll
    for (int s = 0; s < 2; ++s)
#pragma unroll
      for (int c = 0; c < 4; ++c)
        kf[s][c] = *(const bf16x8*)&Kb[(s * 32 + l31) * 64 + (((2 * c + hi) ^ xr) * 8)];

    // S^T[kpos][q] = K . Q^T
    f32x16 s0 = (f32x16)0.0f, s1 = (f32x16)0.0f;
    __builtin_amdgcn_s_setprio(1);
    s0 = __builtin_amdgcn_mfma_f32_32x32x16_bf16(kf[0][0], qf0, s0, 0, 0, 0);
    s1 = __builtin_amdgcn_mfma_f32_32x32x16_bf16(kf[1][0], qf0, s1, 0, 0, 0);
    s0 = __builtin_amdgcn_mfma_f32_32x32x16_bf16(kf[0][1], qf1, s0, 0, 0, 0);
    s1 = __builtin_amdgcn_mfma_f32_32x32x16_bf16(kf[1][1], qf1, s1, 0, 0, 0);
    s0 = __builtin_amdgcn_mfma_f32_32x32x16_bf16(kf[0][2], qf2, s0, 0, 0, 0);
    s1 = __builtin_amdgcn_mfma_f32_32x32x16_bf16(kf[1][2], qf2, s1, 0, 0, 0);
    s0 = __builtin_amdgcn_mfma_f32_32x32x16_bf16(kf[0][3], qf3, s0, 0, 0, 0);
    s1 = __builtin_amdgcn_mfma_f32_32x32x16_bf16(kf[1][3], qf3, s1, 0, 0, 0);
    __builtin_amdgcn_s_setprio(0);

    // causal mask (diagonal tile only; qrel = w*32 + l31)
    if (jt == T - 1) {
      const int qrel = w * 32 + l31;
      const int h4 = hi * 4;
#pragma unroll
      for (int r = 0; r < 16; ++r) {
        const int kp = (r & 3) + ((r >> 2) << 3) + h4;
        s0[r] = (kp <= qrel) ? s0[r] : -1e30f;
        s1[r] = (kp + 32 <= qrel) ? s1[r] : -1e30f;
      }
    }

    // ---- in-register online softmax (lane pair (l31,hi) = one q-row) ----
    float t8[8];
#pragma unroll
    for (int r = 0; r < 8; ++r)
      t8[r] = fmaxf(fmaxf(s0[r], s0[r + 8]), fmaxf(s1[r], s1[r + 8]));
    float tm = fmaxf(fmaxf(fmaxf(t8[0], t8[1]), fmaxf(t8[2], t8[3])),
                     fmaxf(fmaxf(t8[4], t8[5]), fmaxf(t8[6], t8[7])));
    tm = fmaxf(tm, __shfl_xor(tm, 32));
    if (!__all(tm <= mrun)) {
      const float mnew = fmaxf(mrun, tm);
      const float al = fast_exp2((mrun - mnew) * SC);
      mrun = mnew;
      lrun *= al;
#pragma unroll
      for (int r = 0; r < 16; ++r) { o0[r] *= al; o1[r] *= al; }
    }
    const float nb2 = -mrun * SC;
#pragma unroll
    for (int r = 0; r < 16; ++r) {
      s0[r] = fast_exp2(fmaf(s0[r], SC, nb2));
      s1[r] = fast_exp2(fmaf(s1[r], SC, nb2));
    }
    float u8[8];
#pragma unroll
    for (int r = 0; r < 8; ++r)
      u8[r] = (s0[r] + s0[r + 8]) + (s1[r] + s1[r + 8]);
    lrun += ((u8[0] + u8[1]) + (u8[2] + u8[3])) + ((u8[4] + u8[5]) + (u8[6] + u8[7]));

    // ---- pack P to bf16 B-fragments (cvt_pk + permlane32_swap, T12) ----
    bf16x8 pb0, pb1, pb2, pb3;
#define PACK_CHUNK(sv, bb, dst)                                   \
    {                                                             \
      u32 a0 = cvtpk(sv[bb + 0], sv[bb + 1]);                     \
      u32 a1 = cvtpk(sv[bb + 2], sv[bb + 3]);                     \
      u32 a2 = cvtpk(sv[bb + 4], sv[bb + 5]);                     \
      u32 a3 = cvtpk(sv[bb + 6], sv[bb + 7]);                     \
      plswap(a0, a2);                                             \
      plswap(a1, a3);                                             \
      u32x4 fv = {a0, a1, a2, a3};                                \
      dst = __builtin_bit_cast(bf16x8, fv);                       \
    }
    PACK_CHUNK(s0, 0, pb0)
    PACK_CHUNK(s0, 8, pb1)
    PACK_CHUNK(s1, 0, pb2)
    PACK_CHUNK(s1, 8, pb3)
#undef PACK_CHUNK

    // V^T fragments: row = mt*32+l31 (d), want slot 2c+hi -> read slot ^ (row&7)
    bf16x8 vf[2][4];
#pragma unroll
    for (int mt = 0; mt < 2; ++mt)
#pragma unroll
      for (int c = 0; c < 4; ++c)
        vf[mt][c] = *(const bf16x8*)&Vb[(mt * 32 + l31) * 64 + (((2 * c + hi) ^ xr) * 8)];

    // ---- O^T[d][q] += V^T . P^T ----
    __builtin_amdgcn_s_setprio(1);
    o0 = __builtin_amdgcn_mfma_f32_32x32x16_bf16(vf[0][0], pb0, o0, 0, 0, 0);
    o1 = __builtin_amdgcn_mfma_f32_32x32x16_bf16(vf[1][0], pb0, o1, 0, 0, 0);
    o0 = __builtin_amdgcn_mfma_f32_32x32x16_bf16(vf[0][1], pb1, o0, 0, 0, 0);
    o1 = __builtin_amdgcn_mfma_f32_32x32x16_bf16(vf[1][1], pb1, o1, 0, 0, 0);
    o0 = __builtin_amdgcn_mfma_f32_32x32x16_bf16(vf[0][2], pb2, o0, 0, 0, 0);
    o1 = __builtin_amdgcn_mfma_f32_32x32x16_bf16(vf[1][2], pb2, o1, 0, 0, 0);
    o0 = __builtin_amdgcn_mfma_f32_32x32x16_bf16(vf[0][3], pb3, o0, 0, 0, 0);
    o1 = __builtin_amdgcn_mfma_f32_32x32x16_bf16(vf[1][3], pb3, o1, 0, 0, 0);
    __builtin_amdgcn_s_setprio(0);

    __syncthreads();  // drains staged loads + protects buffer reuse
    sel ^= 1;
  }
#undef STAGEA

  // ---- epilogue: combine partner row-sums, normalize, store bf16 (per wave) ----
  const float lt = lrun + __shfl_xor(lrun, 32);
  const float inv = 1.0f / lt;
  u16* aorow = AO + (size_t)(b * 2048 + qb + l31) * 1024 + h * 64 + hi * 4;
#pragma unroll
  for (int g2 = 0; g2 < 4; ++g2) {
    u32 w0 = cvtpk(o0[4 * g2 + 0] * inv, o0[4 * g2 + 1] * inv);
    u32 w1 = cvtpk(o0[4 * g2 + 2] * inv, o0[4 * g2 + 3] * inv);
    u32x2 ww = {w0, w1};
    *(u32x2*)(aorow + g2 * 8) = ww;
  }
#pragma unroll
  for (int g2 = 0; g2 < 4; ++g2) {
    u32 w0 = cvtpk(o1[4 * g2 + 0] * inv, o1[4 * g2 + 1] * inv);
    u32 w1 = cvtpk(o1[4 * g2 + 2] * inv, o1[4 * g2 + 3] * inv);
    u32x2 ww = {w0, w1};
    *(u32x2*)(aorow + 32 + g2 * 8) = ww;
  }
}

extern "C" void kernel_launch(void* const* d_in, const int* in_sizes, int n_in,
                              void* d_out, int out_size, void* d_ws, size_t ws_size,
                              hipStream_t stream) {
  const float* x      = (const float*)d_in[0];
  const float* w_attn = (const float*)d_in[1];
  const float* b_attn = (const float*)d_in[2];
  const float* w_proj = (const float*)d_in[3];
  const float* b_proj = (const float*)d_in[4];
  float* out = (float*)d_out;

  char* ws = (char*)d_ws;
  u16* x_bf  = (u16*)(ws);                    // [4096][1024] bf16 (8 MB); dead after gemm0
  u16* wat_t = (u16*)(ws + 8388608);          // [3072][1024] bf16   (6 MB)
  u16* wpj_t = (u16*)(ws + 14680064);         // [1024][1024] bf16   (2 MB)
  u16* q_ws  = (u16*)(ws + 16777216);         // [B,H,S,d] bf16      (8 MB)
  u16* k_ws  = (u16*)(ws + 25165824);         // [B,H,S,d] bf16      (8 MB)
  u16* v_ws  = (u16*)(ws + 33554432);         // [B,H,S,d] bf16      (8 MB)
  u16* a_ws  = (u16*)(ws + 41943040);         // [B,S,nx]  bf16      (8 MB)
  u16* vT_ws = (u16*)(ws);                    // [B,H,d,S] bf16, reuses x_bf region

  k_cvt<<<4096, 256, 0, stream>>>(x, x_bf, 4194304);
  k_tcvt<<<dim3(96, 32), dim3(32, 8), 0, stream>>>(w_attn, wat_t, 1024, 3072);
  k_tcvt<<<dim3(32, 32), dim3(32, 8), 0, stream>>>(w_proj, wpj_t, 1024, 1024);

  k_gemm<0><<<dim3(24, 32), 256, 0, stream>>>(x_bf, wat_t, b_attn,
                                              q_ws, k_ws, v_ws,
                                              out + 4194304, out + 8388608, nullptr);

  k_vt<<<dim3(32, 32), 256, 0, stream>>>(v_ws, vT_ws);

  k_attn<<<dim3(1024), 128, 0, stream>>>(q_ws, k_ws, vT_ws, a_ws);

  k_gemm<1><<<dim3(8, 32), 256, 0, stream>>>(a_ws, wpj_t, b_proj,
                                             nullptr, nullptr, nullptr,
                                             nullptr, nullptr, out);
}

// Round 13
// 135.547 us; speedup vs baseline: 1.1083x; 1.0178x over previous
//
#include <hip/hip_runtime.h>
#include <stdint.h>
#include <stddef.h>

#define DEVI __device__ __forceinline__

typedef __bf16 bf16x8 __attribute__((ext_vector_type(8)));
typedef float  f32x4  __attribute__((ext_vector_type(4)));
typedef float  f32x16 __attribute__((ext_vector_type(16)));
typedef unsigned short u16;
typedef uint32_t u32;
typedef u16 u16x8 __attribute__((ext_vector_type(8)));
typedef u16 u16x4 __attribute__((ext_vector_type(4)));
typedef u32 u32x2 __attribute__((ext_vector_type(2)));
typedef u32 u32x4 __attribute__((ext_vector_type(4)));

typedef __attribute__((address_space(1))) void as1_void;
typedef __attribute__((address_space(3))) void as3_void;

static constexpr float SC = 0.18033688011112042f;  // (1/8) * log2(e)

DEVI u16 f2bf(float f) {
  uint32_t u = __builtin_bit_cast(uint32_t, f);
  u += 0x7fffu + ((u >> 16) & 1u);
  return (u16)(u >> 16);
}

DEVI void gload_lds16(const void* g, void* l) {
  __builtin_amdgcn_global_load_lds((as1_void*)(void*)g, (as3_void*)l, 16, 0, 0);
}

#if __has_builtin(__builtin_amdgcn_exp2f)
DEVI float fast_exp2(float x) { return __builtin_amdgcn_exp2f(x); }
#else
DEVI float fast_exp2(float x) { return exp2f(x); }
#endif

DEVI u32 cvtpk(float lo, float hi) {
  u32 r;
  asm("v_cvt_pk_bf16_f32 %0, %1, %2" : "=v"(r) : "v"(lo), "v"(hi));
  return r;
}
DEVI void plswap(u32& a, u32& b) {
  asm("v_permlane32_swap_b32 %0, %1" : "+v"(a), "+v"(b));
}

// ---------------- elementwise fp32 -> bf16 ----------------
__global__ __launch_bounds__(256) void k_cvt(const float* __restrict__ in,
                                             u16* __restrict__ out, int n) {
  int i = (blockIdx.x * 256 + threadIdx.x) * 4;
  if (i >= n) return;
  const float4 v = *(const float4*)(in + i);
  u16x4 o = { f2bf(v.x), f2bf(v.y), f2bf(v.z), f2bf(v.w) };
  *(u16x4*)(out + i) = o;
}

// ------------- transpose + convert: in fp32 [R][C] -> out bf16 [C][R] -------------
__global__ __launch_bounds__(256) void k_tcvt(const float* __restrict__ in,
                                              u16* __restrict__ out, int R, int C) {
  __shared__ float tile[32][33];
  const int c0 = blockIdx.x * 32, r0 = blockIdx.y * 32;
  const int tx = threadIdx.x, ty = threadIdx.y;
#pragma unroll
  for (int i = ty; i < 32; i += 8)
    tile[i][tx] = in[(size_t)(r0 + i) * C + (c0 + tx)];
  __syncthreads();
#pragma unroll
  for (int i = ty; i < 32; i += 8)
    out[(size_t)(c0 + i) * R + (r0 + tx)] = f2bf(tile[tx][i]);
}

// ------------- per-head bf16 transpose: [S 2048][d 64] -> [d 64][S 2048] -------------
__global__ __launch_bounds__(256) void k_vt(const u16* __restrict__ in,
                                            u16* __restrict__ out) {
  __shared__ u16 tile[64][72];
  const int tid = threadIdx.x;
  const int s0 = blockIdx.x * 64;
  const int bh = blockIdx.y;
  const size_t ib = (size_t)bh * 131072;
#pragma unroll
  for (int it = 0; it < 2; ++it) {
    const int r = (tid >> 3) + it * 32;
    const int c8 = (tid & 7) * 8;
    u16x8 v = *(const u16x8*)(in + ib + (size_t)(s0 + r) * 64 + c8);
    *(u16x8*)&tile[r][c8] = v;
  }
  __syncthreads();
#pragma unroll
  for (int it = 0; it < 2; ++it) {
    const int d = (tid >> 3) + it * 32;
    const int s8 = (tid & 7) * 8;
    u16x8 v;
#pragma unroll
    for (int jj = 0; jj < 8; ++jj) v[jj] = tile[s8 + jj][d];
    *(u16x8*)(out + ib + (size_t)d * 2048 + s0 + s8) = v;
  }
}

// ---------------- GEMM: C[M][N] = A[M][K] * Bt[N][K]^T  (bf16 in, fp32 acc) ----------------
// Tri-buffered LDS + counted s_waitcnt vmcnt(4) + raw s_barrier (T3/T4) +
// T1 XCD-chunked bid remap. Clean coalesced epilogue.
template <int EPI>
__global__ __launch_bounds__(256) void k_gemm(
    const u16* __restrict__ A, const u16* __restrict__ Bt,
    const float* __restrict__ bias,
    u16* __restrict__ wq, u16* __restrict__ wk, u16* __restrict__ wv,
    float* __restrict__ pk, float* __restrict__ pv, float* __restrict__ of) {
  constexpr int K = 1024;
  constexpr int NT = K / 32;
  __shared__ __align__(16) u16 Ash[3][128 * 32];
  __shared__ __align__(16) u16 Bsh[3][128 * 32];
  const int tid = threadIdx.x;
  const int lane = tid & 63, wid = tid >> 6;
  const int wm = wid >> 1, wn = wid & 1;
  const int lr = lane & 15, lg = lane >> 4;

  // T1: XCD-chunked remap (nwg % 8 == 0 in both uses -> bijective)
  const int nwgx = gridDim.x;
  const int nwg = nwgx * gridDim.y;
  int lbid = blockIdx.y * nwgx + blockIdx.x;
  lbid = (lbid & 7) * (nwg >> 3) + (lbid >> 3);
  const int m0 = (lbid / nwgx) * 128, n0 = (lbid % nwgx) * 128;

  const int c = wid * 64 + lane;  // 16B chunk id, 0..255
  const u16* Ag1 = A + (size_t)(m0 + (c >> 2)) * K + (c & 3) * 8;
  const u16* Ag2 = A + (size_t)(m0 + 64 + (c >> 2)) * K + (c & 3) * 8;
  const u16* Bg1 = Bt + (size_t)(n0 + (c >> 2)) * K + (c & 3) * 8;
  const u16* Bg2 = Bt + (size_t)(n0 + 64 + (c >> 2)) * K + (c & 3) * 8;

  f32x4 acc[4][4];
#pragma unroll
  for (int i = 0; i < 4; ++i)
#pragma unroll
    for (int j = 0; j < 4; ++j) acc[i][j] = (f32x4)0.0f;

#define STAGE(sel, kk)                                        \
  {                                                           \
    gload_lds16(Ag1 + (kk), &Ash[sel][wid * 512]);            \
    gload_lds16(Ag2 + (kk), &Ash[sel][2048 + wid * 512]);     \
    gload_lds16(Bg1 + (kk), &Bsh[sel][wid * 512]);            \
    gload_lds16(Bg2 + (kk), &Bsh[sel][2048 + wid * 512]);     \
  }

  STAGE(0, 0)
  STAGE(1, 32)
  asm volatile("s_waitcnt vmcnt(4)" ::: "memory");
  __builtin_amdgcn_sched_barrier(0);
  __builtin_amdgcn_s_barrier();
  __builtin_amdgcn_sched_barrier(0);

  int cur = 0;
  for (int j = 0; j < NT; ++j) {
    const bool pf = (j + 2 < NT);
    int nb = cur + 2; if (nb >= 3) nb -= 3;
    if (pf) STAGE(nb, (j + 2) * 32)
    bf16x8 af[4], bfr[4];
#pragma unroll
    for (int f = 0; f < 4; ++f) {
      af[f]  = *(const bf16x8*)&Ash[cur][(wm * 64 + f * 16 + lr) * 32 + lg * 8];
      bfr[f] = *(const bf16x8*)&Bsh[cur][(wn * 64 + f * 16 + lr) * 32 + lg * 8];
    }
    __builtin_amdgcn_s_setprio(1);
#pragma unroll
    for (int i = 0; i < 4; ++i)
#pragma unroll
      for (int jj = 0; jj < 4; ++jj)
        acc[i][jj] = __builtin_amdgcn_mfma_f32_16x16x32_bf16(af[i], bfr[jj], acc[i][jj], 0, 0, 0);
    __builtin_amdgcn_s_setprio(0);
    if (pf) asm volatile("s_waitcnt vmcnt(4)" ::: "memory");
    else    asm volatile("s_waitcnt vmcnt(0)" ::: "memory");
    __builtin_amdgcn_sched_barrier(0);
    __builtin_amdgcn_s_barrier();
    __builtin_amdgcn_sched_barrier(0);
    cur = (cur + 1 == 3) ? 0 : cur + 1;
  }
#undef STAGE

  if constexpr (EPI == 0) {
#pragma unroll
    for (int j = 0; j < 4; ++j) {
      const int n = n0 + wn * 64 + j * 16 + lr;
      const float bv = bias[n];
      const int sec = n >> 10;
      const int nn = n & 1023;
      const int h = nn >> 6, dd = nn & 63;
#pragma unroll
      for (int i = 0; i < 4; ++i) {
        const int mb = m0 + wm * 64 + i * 16 + lg * 4;
        const int bb = mb >> 11, ss = mb & 2047;
        const size_t ib = (size_t)(bb * 16 + h) * 131072 + (size_t)ss * 64 + dd;
        if (sec == 0) {
#pragma unroll
          for (int r = 0; r < 4; ++r)
            wq[ib + (size_t)r * 64] = f2bf(acc[i][j][r] + bv);
        } else if (sec == 1) {
#pragma unroll
          for (int r = 0; r < 4; ++r) {
            const float v = acc[i][j][r] + bv;
            wk[ib + (size_t)r * 64] = f2bf(v);
            pk[ib + (size_t)r * 64] = v;
          }
        } else {
#pragma unroll
          for (int r = 0; r < 4; ++r) {
            const float v = acc[i][j][r] + bv;
            wv[ib + (size_t)r * 64] = f2bf(v);
            pv[ib + (size_t)r * 64] = v;
          }
        }
      }
    }
  } else {
#pragma unroll
    for (int j = 0; j < 4; ++j) {
      const int n = n0 + wn * 64 + j * 16 + lr;
      const float bv = bias[n];
#pragma unroll
      for (int i = 0; i < 4; ++i) {
        const int mb = m0 + wm * 64 + i * 16 + lg * 4;
#pragma unroll
        for (int r = 0; r < 4; ++r)
          of[(size_t)(mb + r) * 1024 + n] = acc[i][j][r] + bv;
      }
    }
  }
}

// ---------------- causal flash attention: uniform-work blocks, barrier-free loop ----------------
// 1024 blocks x 128 thr (2 waves). Block = (bh = bid&31 [XCD-pinned], p = bid>>5).
// Phase t: 32-row q-tile qtl = t ? 63-p : p; T = qtl/2+1 KV tiles; wave0 covers
// [0,mid), wave1 [mid,T) -> per-wave 16-17 iters per BLOCK-phase, uniform across
// ALL blocks (T_A+T_B = 33/34) -> flat 8 waves/CU, no tail.
// Per-wave PRIVATE K LDS double-buffer (2x8KB/wave, 32KB/block) -> NO main-loop
// barriers; counted vmcnt only (all staging = own asm/builtins, fixed order:
// V regs first, K-next second => vmcnt(16) guards K(jt), vmcnt(8) guards V(jt)).
// V^T loaded global->reg via inline-asm dwordx4 (deterministic vmcnt counting).
// Cross-wave flash-combine per phase via 2 __syncthreads (overlay on w0 K area).
__global__ __launch_bounds__(128, 2) void k_attn(const u16* __restrict__ Q,
                                                 const u16* __restrict__ Kp,
                                                 const u16* __restrict__ VT,
                                                 u16* __restrict__ AO) {
  __shared__ __align__(16) u16 Ksh[2][2][4096];  // [wave][buf][64 kpos x 64 d], swizzled

  const int tid = threadIdx.x;
  const int lane = tid & 63, w = tid >> 6;    // w in {0,1}
  const int l31 = lane & 31, hi = lane >> 5;
  const int bid = blockIdx.x;
  const int bh = bid & 31;                    // bh%8 == bid%8 -> XCD-pinned
  const int p = bid >> 5;                     // 0..31
  const int b = bh >> 4, h = bh & 15;
  const size_t hb = (size_t)bh * (2048 * 64);
  const int xr = l31 & 7;                     // read-side swizzle key

  // K staging source (pre-swizzled): row = c*8 + lane>>3, slot = (lane&7)^(lane>>3)
  const u16* Kg = Kp + hb + (size_t)(lane >> 3) * 64 + (size_t)(((lane & 7) ^ (lane >> 3)) * 8);
  // V^T source: d = mt*32 + l31, kpos = jt*64 + c*16 + hi*8
  const u16* Vg = VT + hb + (size_t)l31 * 2048 + hi * 8;

  float* OslB = (float*)&Ksh[0][0][0];   // [32][64] f32, 8 KB (w0 buf0)
  float* ML   = (float*)&Ksh[0][1][0];   // m[64], l[64] (w0 buf1 head)

#define STAGEK(sel, jt)                                       \
  {                                                           \
    u16* kd = &Ksh[w][sel][0];                                \
    const u16* ks = Kg + (size_t)(jt) * 4096;                 \
    gload_lds16(ks,        kd);                               \
    gload_lds16(ks +  512, kd +  512);                        \
    gload_lds16(ks + 1024, kd + 1024);                        \
    gload_lds16(ks + 1536, kd + 1536);                        \
    gload_lds16(ks + 2048, kd + 2048);                        \
    gload_lds16(ks + 2560, kd + 2560);                        \
    gload_lds16(ks + 3072, kd + 3072);                        \
    gload_lds16(ks + 3584, kd + 3584);                        \
  }

#define GL16(dst, ptr, IMM)                                           \
  asm volatile("global_load_dwordx4 %0, %1, off offset:" #IMM         \
               : "=v"(dst) : "v"(ptr));

#define LOADV(jt)                                             \
  {                                                           \
    const u16* vp0 = Vg + (size_t)(jt) * 64;                  \
    const u16* vp1 = vp0 + 65536;                             \
    GL16(vv[0][0], vp0, 0)  GL16(vv[0][1], vp0, 32)           \
    GL16(vv[0][2], vp0, 64) GL16(vv[0][3], vp0, 96)           \
    GL16(vv[1][0], vp1, 0)  GL16(vv[1][1], vp1, 32)           \
    GL16(vv[1][2], vp1, 64) GL16(vv[1][3], vp1, 96)           \
  }

  for (int t = 0; t < 2; ++t) {
    const int qtl = t ? (63 - p) : p;
    const int T = (qtl >> 1) + 1;
    const int mid = (T + 1) >> 1;
    const int lo  = w ? mid : 0;
    const int hiE = w ? T : mid;
    const int qb = qtl * 32;

    const u16* Qp2 = Q + hb + (size_t)(qb + l31) * 64 + hi * 8;
    const bf16x8 qf0 = *(const bf16x8*)(Qp2);
    const bf16x8 qf1 = *(const bf16x8*)(Qp2 + 16);
    const bf16x8 qf2 = *(const bf16x8*)(Qp2 + 32);
    const bf16x8 qf3 = *(const bf16x8*)(Qp2 + 48);

    f32x16 o0 = (f32x16)0.0f, o1 = (f32x16)0.0f;
    float mrun = -1e30f, lrun = 0.0f;

    if (lo < hiE) {
      STAGEK(0, lo)
      int cur = 0;
      for (int jt = lo; jt < hiE; ++jt) {
        const bool hn = (jt + 1 < hiE);
        u32x4 vv[2][4];
        LOADV(jt)                       // V(jt) -> regs (older)
        if (hn) STAGEK(cur ^ 1, jt + 1) // K(jt+1) -> alt buf (younger)
        // wait K(jt) done: allow V(8) + K-next(8) in flight
        if (hn) asm volatile("s_waitcnt vmcnt(16)" ::: "memory");
        else    asm volatile("s_waitcnt vmcnt(8)"  ::: "memory");
        __builtin_amdgcn_sched_barrier(0);

        const u16* Kb = &Ksh[w][cur][0];
        bf16x8 kf[2][4];
#pragma unroll
        for (int s = 0; s < 2; ++s)
#pragma unroll
          for (int c = 0; c < 4; ++c)
            kf[s][c] = *(const bf16x8*)&Kb[(s * 32 + l31) * 64 + (((2 * c + hi) ^ xr) * 8)];

        // S^T[kpos][q] = K . Q^T
        f32x16 s0 = (f32x16)0.0f, s1 = (f32x16)0.0f;
        __builtin_amdgcn_s_setprio(1);
        s0 = __builtin_amdgcn_mfma_f32_32x32x16_bf16(kf[0][0], qf0, s0, 0, 0, 0);
        s1 = __builtin_amdgcn_mfma_f32_32x32x16_bf16(kf[1][0], qf0, s1, 0, 0, 0);
        s0 = __builtin_amdgcn_mfma_f32_32x32x16_bf16(kf[0][1], qf1, s0, 0, 0, 0);
        s1 = __builtin_amdgcn_mfma_f32_32x32x16_bf16(kf[1][1], qf1, s1, 0, 0, 0);
        s0 = __builtin_amdgcn_mfma_f32_32x32x16_bf16(kf[0][2], qf2, s0, 0, 0, 0);
        s1 = __builtin_amdgcn_mfma_f32_32x32x16_bf16(kf[1][2], qf2, s1, 0, 0, 0);
        s0 = __builtin_amdgcn_mfma_f32_32x32x16_bf16(kf[0][3], qf3, s0, 0, 0, 0);
        s1 = __builtin_amdgcn_mfma_f32_32x32x16_bf16(kf[1][3], qf3, s1, 0, 0, 0);
        __builtin_amdgcn_s_setprio(0);

        // causal mask (diagonal tile only; qrel = (qtl&1)*32 + l31)
        if (jt == T - 1) {
          const int qrel = (qtl & 1) * 32 + l31;
          const int h4 = hi * 4;
#pragma unroll
          for (int r = 0; r < 16; ++r) {
            const int kp = (r & 3) + ((r >> 2) << 3) + h4;
            s0[r] = (kp <= qrel) ? s0[r] : -1e30f;
            s1[r] = (kp + 32 <= qrel) ? s1[r] : -1e30f;
          }
        }

        // ---- in-register online softmax (lane pair (l31,hi) = one q-row) ----
        float t8[8];
#pragma unroll
        for (int r = 0; r < 8; ++r)
          t8[r] = fmaxf(fmaxf(s0[r], s0[r + 8]), fmaxf(s1[r], s1[r + 8]));
        float tm = fmaxf(fmaxf(fmaxf(t8[0], t8[1]), fmaxf(t8[2], t8[3])),
                         fmaxf(fmaxf(t8[4], t8[5]), fmaxf(t8[6], t8[7])));
        tm = fmaxf(tm, __shfl_xor(tm, 32));
        if (!__all(tm <= mrun)) {
          const float mnew = fmaxf(mrun, tm);
          const float al = fast_exp2((mrun - mnew) * SC);
          mrun = mnew;
          lrun *= al;
#pragma unroll
          for (int r = 0; r < 16; ++r) { o0[r] *= al; o1[r] *= al; }
        }
        const float nb2 = -mrun * SC;
#pragma unroll
        for (int r = 0; r < 16; ++r) {
          s0[r] = fast_exp2(fmaf(s0[r], SC, nb2));
          s1[r] = fast_exp2(fmaf(s1[r], SC, nb2));
        }
        float u8[8];
#pragma unroll
        for (int r = 0; r < 8; ++r)
          u8[r] = (s0[r] + s0[r + 8]) + (s1[r] + s1[r + 8]);
        lrun += ((u8[0] + u8[1]) + (u8[2] + u8[3])) + ((u8[4] + u8[5]) + (u8[6] + u8[7]));

        // ---- pack P to bf16 B-fragments (cvt_pk + permlane32_swap, T12) ----
        bf16x8 pb0, pb1, pb2, pb3;
#define PACK_CHUNK(sv, bb, dst)                                   \
        {                                                         \
          u32 a0 = cvtpk(sv[bb + 0], sv[bb + 1]);                 \
          u32 a1 = cvtpk(sv[bb + 2], sv[bb + 3]);                 \
          u32 a2 = cvtpk(sv[bb + 4], sv[bb + 5]);                 \
          u32 a3 = cvtpk(sv[bb + 6], sv[bb + 7]);                 \
          plswap(a0, a2);                                         \
          plswap(a1, a3);                                         \
          u32x4 fv = {a0, a1, a2, a3};                            \
          dst = __builtin_bit_cast(bf16x8, fv);                   \
        }
        PACK_CHUNK(s0, 0, pb0)
        PACK_CHUNK(s0, 8, pb1)
        PACK_CHUNK(s1, 0, pb2)
        PACK_CHUNK(s1, 8, pb3)
#undef PACK_CHUNK

        // wait V(jt) regs: allow K(jt+1) in flight
        if (hn) asm volatile("s_waitcnt vmcnt(8)" ::: "memory");
        else    asm volatile("s_waitcnt vmcnt(0)" ::: "memory");
        __builtin_amdgcn_sched_barrier(0);

        const bf16x8 vf00 = __builtin_bit_cast(bf16x8, vv[0][0]);
        const bf16x8 vf01 = __builtin_bit_cast(bf16x8, vv[0][1]);
        const bf16x8 vf02 = __builtin_bit_cast(bf16x8, vv[0][2]);
        const bf16x8 vf03 = __builtin_bit_cast(bf16x8, vv[0][3]);
        const bf16x8 vf10 = __builtin_bit_cast(bf16x8, vv[1][0]);
        const bf16x8 vf11 = __builtin_bit_cast(bf16x8, vv[1][1]);
        const bf16x8 vf12 = __builtin_bit_cast(bf16x8, vv[1][2]);
        const bf16x8 vf13 = __builtin_bit_cast(bf16x8, vv[1][3]);

        // ---- O^T[d][q] += V^T . P^T ----
        __builtin_amdgcn_s_setprio(1);
        o0 = __builtin_amdgcn_mfma_f32_32x32x16_bf16(vf00, pb0, o0, 0, 0, 0);
        o1 = __builtin_amdgcn_mfma_f32_32x32x16_bf16(vf10, pb0, o1, 0, 0, 0);
        o0 = __builtin_amdgcn_mfma_f32_32x32x16_bf16(vf01, pb1, o0, 0, 0, 0);
        o1 = __builtin_amdgcn_mfma_f32_32x32x16_bf16(vf11, pb1, o1, 0, 0, 0);
        o0 = __builtin_amdgcn_mfma_f32_32x32x16_bf16(vf02, pb2, o0, 0, 0, 0);
        o1 = __builtin_amdgcn_mfma_f32_32x32x16_bf16(vf12, pb2, o1, 0, 0, 0);
        o0 = __builtin_amdgcn_mfma_f32_32x32x16_bf16(vf03, pb3, o0, 0, 0, 0);
        o1 = __builtin_amdgcn_mfma_f32_32x32x16_bf16(vf13, pb3, o1, 0, 0, 0);
        __builtin_amdgcn_s_setprio(0);

        cur ^= 1;
      }
    }

    // ---- cross-wave flash combine (2 barriers; overlay on w0's K area) ----
    __syncthreads();   // all loop reads done block-wide; drains counters
    if (w == 1) {
#pragma unroll
      for (int r = 0; r < 16; ++r) {
        OslB[r * 64 + lane]        = o0[r];
        OslB[(16 + r) * 64 + lane] = o1[r];
      }
      ML[lane]      = mrun;
      ML[64 + lane] = lrun;
    }
    __syncthreads();
    if (w == 0) {
      const float mB = ML[lane];
      const float lB = ML[64 + lane];
      const float m  = fmaxf(mrun, mB);
      const float al = fast_exp2((mrun - m) * SC);
      const float bt = fast_exp2((mB - m) * SC);
      lrun = lrun * al + lB * bt;
#pragma unroll
      for (int r = 0; r < 16; ++r) {
        o0[r] = o0[r] * al + OslB[r * 64 + lane] * bt;
        o1[r] = o1[r] * al + OslB[(16 + r) * 64 + lane] * bt;
      }

      // ---- epilogue: combine partner row-sums, normalize, store bf16 ----
      const float lt = lrun + __shfl_xor(lrun, 32);
      const float inv = 1.0f / lt;
      u16* aorow = AO + (size_t)(b * 2048 + qb + l31) * 1024 + h * 64 + hi * 4;
#pragma unroll
      for (int g2 = 0; g2 < 4; ++g2) {
        u32 w0s = cvtpk(o0[4 * g2 + 0] * inv, o0[4 * g2 + 1] * inv);
        u32 w1s = cvtpk(o0[4 * g2 + 2] * inv, o0[4 * g2 + 3] * inv);
        u32x2 ww = {w0s, w1s};
        *(u32x2*)(aorow + g2 * 8) = ww;
      }
#pragma unroll
      for (int g2 = 0; g2 < 4; ++g2) {
        u32 w0s = cvtpk(o1[4 * g2 + 0] * inv, o1[4 * g2 + 1] * inv);
        u32 w1s = cvtpk(o1[4 * g2 + 2] * inv, o1[4 * g2 + 3] * inv);
        u32x2 ww = {w0s, w1s};
        *(u32x2*)(aorow + 32 + g2 * 8) = ww;
      }
      // ensure Osl reads drained before next phase re-stages this area
      asm volatile("s_waitcnt lgkmcnt(0)" ::: "memory");
      __builtin_amdgcn_sched_barrier(0);
    }
  }
#undef STAGEK
#undef LOADV
#undef GL16
}

extern "C" void kernel_launch(void* const* d_in, const int* in_sizes, int n_in,
                              void* d_out, int out_size, void* d_ws, size_t ws_size,
                              hipStream_t stream) {
  const float* x      = (const float*)d_in[0];
  const float* w_attn = (const float*)d_in[1];
  const float* b_attn = (const float*)d_in[2];
  const float* w_proj = (const float*)d_in[3];
  const float* b_proj = (const float*)d_in[4];
  float* out = (float*)d_out;

  char* ws = (char*)d_ws;
  u16* x_bf  = (u16*)(ws);                    // [4096][1024] bf16 (8 MB); dead after gemm0
  u16* wat_t = (u16*)(ws + 8388608);          // [3072][1024] bf16   (6 MB)
  u16* wpj_t = (u16*)(ws + 14680064);         // [1024][1024] bf16   (2 MB)
  u16* q_ws  = (u16*)(ws + 16777216);         // [B,H,S,d] bf16      (8 MB)
  u16* k_ws  = (u16*)(ws + 25165824);         // [B,H,S,d] bf16      (8 MB)
  u16* v_ws  = (u16*)(ws + 33554432);         // [B,H,S,d] bf16      (8 MB)
  u16* a_ws  = (u16*)(ws + 41943040);         // [B,S,nx]  bf16      (8 MB)
  u16* vT_ws = (u16*)(ws);                    // [B,H,d,S] bf16, reuses x_bf region

  k_cvt<<<4096, 256, 0, stream>>>(x, x_bf, 4194304);
  k_tcvt<<<dim3(96, 32), dim3(32, 8), 0, stream>>>(w_attn, wat_t, 1024, 3072);
  k_tcvt<<<dim3(32, 32), dim3(32, 8), 0, stream>>>(w_proj, wpj_t, 1024, 1024);

  k_gemm<0><<<dim3(24, 32), 256, 0, stream>>>(x_bf, wat_t, b_attn,
                                              q_ws, k_ws, v_ws,
                                              out + 4194304, out + 8388608, nullptr);

  k_vt<<<dim3(32, 32), 256, 0, stream>>>(v_ws, vT_ws);

  k_attn<<<dim3(1024), 128, 0, stream>>>(q_ws, k_ws, vT_ws, a_ws);

  k_gemm<1><<<dim3(8, 32), 256, 0, stream>>>(a_ws, wpj_t, b_proj,
                                             nullptr, nullptr, nullptr,
                                             nullptr, nullptr, out);
}

// Round 14
// 132.214 us; speedup vs baseline: 1.1362x; 1.0252x over previous
//
#include <hip/hip_runtime.h>
#include <stdint.h>
#include <stddef.h>

#define DEVI __device__ __forceinline__

typedef __bf16 bf16x8 __attribute__((ext_vector_type(8)));
typedef float  f32x4  __attribute__((ext_vector_type(4)));
typedef float  f32x16 __attribute__((ext_vector_type(16)));
typedef unsigned short u16;
typedef uint32_t u32;
typedef u16 u16x8 __attribute__((ext_vector_type(8)));
typedef u16 u16x4 __attribute__((ext_vector_type(4)));
typedef u32 u32x2 __attribute__((ext_vector_type(2)));
typedef u32 u32x4 __attribute__((ext_vector_type(4)));

typedef __attribute__((address_space(1))) void as1_void;
typedef __attribute__((address_space(3))) void as3_void;

static constexpr float SC = 0.18033688011112042f;  // (1/8) * log2(e)

DEVI u16 f2bf(float f) {
  uint32_t u = __builtin_bit_cast(uint32_t, f);
  u += 0x7fffu + ((u >> 16) & 1u);
  return (u16)(u >> 16);
}

DEVI void gload_lds16(const void* g, void* l) {
  __builtin_amdgcn_global_load_lds((as1_void*)(void*)g, (as3_void*)l, 16, 0, 0);
}

#if __has_builtin(__builtin_amdgcn_exp2f)
DEVI float fast_exp2(float x) { return __builtin_amdgcn_exp2f(x); }
#else
DEVI float fast_exp2(float x) { return exp2f(x); }
#endif

DEVI u32 cvtpk(float lo, float hi) {
  u32 r;
  asm("v_cvt_pk_bf16_f32 %0, %1, %2" : "=v"(r) : "v"(lo), "v"(hi));
  return r;
}
DEVI void plswap(u32& a, u32& b) {
  asm("v_permlane32_swap_b32 %0, %1" : "+v"(a), "+v"(b));
}

// ---------------- elementwise fp32 -> bf16 ----------------
__global__ __launch_bounds__(256) void k_cvt(const float* __restrict__ in,
                                             u16* __restrict__ out, int n) {
  int i = (blockIdx.x * 256 + threadIdx.x) * 4;
  if (i >= n) return;
  const float4 v = *(const float4*)(in + i);
  u16x4 o = { f2bf(v.x), f2bf(v.y), f2bf(v.z), f2bf(v.w) };
  *(u16x4*)(out + i) = o;
}

// ------------- transpose + convert: in fp32 [R][C] -> out bf16 [C][R] -------------
__global__ __launch_bounds__(256) void k_tcvt(const float* __restrict__ in,
                                              u16* __restrict__ out, int R, int C) {
  __shared__ float tile[32][33];
  const int c0 = blockIdx.x * 32, r0 = blockIdx.y * 32;
  const int tx = threadIdx.x, ty = threadIdx.y;
#pragma unroll
  for (int i = ty; i < 32; i += 8)
    tile[i][tx] = in[(size_t)(r0 + i) * C + (c0 + tx)];
  __syncthreads();
#pragma unroll
  for (int i = ty; i < 32; i += 8)
    out[(size_t)(c0 + i) * R + (r0 + tx)] = f2bf(tile[tx][i]);
}

// ------------- per-head bf16 transpose: [S 2048][d 64] -> [d 64][S 2048] -------------
__global__ __launch_bounds__(256) void k_vt(const u16* __restrict__ in,
                                            u16* __restrict__ out) {
  __shared__ u16 tile[64][72];
  const int tid = threadIdx.x;
  const int s0 = blockIdx.x * 64;
  const int bh = blockIdx.y;
  const size_t ib = (size_t)bh * 131072;
#pragma unroll
  for (int it = 0; it < 2; ++it) {
    const int r = (tid >> 3) + it * 32;
    const int c8 = (tid & 7) * 8;
    u16x8 v = *(const u16x8*)(in + ib + (size_t)(s0 + r) * 64 + c8);
    *(u16x8*)&tile[r][c8] = v;
  }
  __syncthreads();
#pragma unroll
  for (int it = 0; it < 2; ++it) {
    const int d = (tid >> 3) + it * 32;
    const int s8 = (tid & 7) * 8;
    u16x8 v;
#pragma unroll
    for (int jj = 0; jj < 8; ++jj) v[jj] = tile[s8 + jj][d];
    *(u16x8*)(out + ib + (size_t)d * 2048 + s0 + s8) = v;
  }
}

// ---------------- GEMM: C[M][N] = A[M][K] * Bt[N][K]^T  (bf16 in, fp32 acc) ----------------
// Tri-buffered LDS + counted s_waitcnt vmcnt(4) + raw s_barrier (T3/T4) +
// T1 XCD-chunked bid remap + T2 LDS XOR-swizzle (both-sides involution, rule #21):
// staging source slot = (c&3)^((c>>3)&3) [LDS dest linear], read slot = lg^((lr>>1)&3).
// Spreads each 16-lane phase group across all 8 bank-quads -> conflict-free ds_read_b128.
template <int EPI>
__global__ __launch_bounds__(256) void k_gemm(
    const u16* __restrict__ A, const u16* __restrict__ Bt,
    const float* __restrict__ bias,
    u16* __restrict__ wq, u16* __restrict__ wk, u16* __restrict__ wv,
    float* __restrict__ pk, float* __restrict__ pv, float* __restrict__ of) {
  constexpr int K = 1024;
  constexpr int NT = K / 32;
  __shared__ __align__(16) u16 Ash[3][128 * 32];
  __shared__ __align__(16) u16 Bsh[3][128 * 32];
  const int tid = threadIdx.x;
  const int lane = tid & 63, wid = tid >> 6;
  const int wm = wid >> 1, wn = wid & 1;
  const int lr = lane & 15, lg = lane >> 4;

  // T1: XCD-chunked remap (nwg % 8 == 0 in both uses -> bijective)
  const int nwgx = gridDim.x;
  const int nwg = nwgx * gridDim.y;
  int lbid = blockIdx.y * nwgx + blockIdx.x;
  lbid = (lbid & 7) * (nwg >> 3) + (lbid >> 3);
  const int m0 = (lbid / nwgx) * 128, n0 = (lbid % nwgx) * 128;

  const int c = wid * 64 + lane;  // 16B chunk id, 0..255
  // T2: pre-swizzled source slot (row = c>>2; (row>>1)&3 == (c>>3)&3)
  const int sw = (((c & 3) ^ ((c >> 3) & 3)) * 8);
  const u16* Ag1 = A + (size_t)(m0 + (c >> 2)) * K + sw;
  const u16* Ag2 = A + (size_t)(m0 + 64 + (c >> 2)) * K + sw;
  const u16* Bg1 = Bt + (size_t)(n0 + (c >> 2)) * K + sw;
  const u16* Bg2 = Bt + (size_t)(n0 + 64 + (c >> 2)) * K + sw;

  f32x4 acc[4][4];
#pragma unroll
  for (int i = 0; i < 4; ++i)
#pragma unroll
    for (int j = 0; j < 4; ++j) acc[i][j] = (f32x4)0.0f;

#define STAGE(sel, kk)                                        \
  {                                                           \
    gload_lds16(Ag1 + (kk), &Ash[sel][wid * 512]);            \
    gload_lds16(Ag2 + (kk), &Ash[sel][2048 + wid * 512]);     \
    gload_lds16(Bg1 + (kk), &Bsh[sel][wid * 512]);            \
    gload_lds16(Bg2 + (kk), &Bsh[sel][2048 + wid * 512]);     \
  }

  STAGE(0, 0)
  STAGE(1, 32)
  asm volatile("s_waitcnt vmcnt(4)" ::: "memory");
  __builtin_amdgcn_sched_barrier(0);
  __builtin_amdgcn_s_barrier();
  __builtin_amdgcn_sched_barrier(0);

  const int xg = (lr >> 1) & 3;  // T2 read-side swizzle key (== (row>>1)&3)

  int cur = 0;
  for (int j = 0; j < NT; ++j) {
    const bool pf = (j + 2 < NT);
    int nb = cur + 2; if (nb >= 3) nb -= 3;
    if (pf) STAGE(nb, (j + 2) * 32)
    bf16x8 af[4], bfr[4];
#pragma unroll
    for (int f = 0; f < 4; ++f) {
      af[f]  = *(const bf16x8*)&Ash[cur][(wm * 64 + f * 16 + lr) * 32 + ((lg ^ xg) * 8)];
      bfr[f] = *(const bf16x8*)&Bsh[cur][(wn * 64 + f * 16 + lr) * 32 + ((lg ^ xg) * 8)];
    }
    __builtin_amdgcn_s_setprio(1);
#pragma unroll
    for (int i = 0; i < 4; ++i)
#pragma unroll
      for (int jj = 0; jj < 4; ++jj)
        acc[i][jj] = __builtin_amdgcn_mfma_f32_16x16x32_bf16(af[i], bfr[jj], acc[i][jj], 0, 0, 0);
    __builtin_amdgcn_s_setprio(0);
    if (pf) asm volatile("s_waitcnt vmcnt(4)" ::: "memory");
    else    asm volatile("s_waitcnt vmcnt(0)" ::: "memory");
    __builtin_amdgcn_sched_barrier(0);
    __builtin_amdgcn_s_barrier();
    __builtin_amdgcn_sched_barrier(0);
    cur = (cur + 1 == 3) ? 0 : cur + 1;
  }
#undef STAGE

  if constexpr (EPI == 0) {
#pragma unroll
    for (int j = 0; j < 4; ++j) {
      const int n = n0 + wn * 64 + j * 16 + lr;
      const float bv = bias[n];
      const int sec = n >> 10;
      const int nn = n & 1023;
      const int h = nn >> 6, dd = nn & 63;
#pragma unroll
      for (int i = 0; i < 4; ++i) {
        const int mb = m0 + wm * 64 + i * 16 + lg * 4;
        const int bb = mb >> 11, ss = mb & 2047;
        const size_t ib = (size_t)(bb * 16 + h) * 131072 + (size_t)ss * 64 + dd;
        if (sec == 0) {
#pragma unroll
          for (int r = 0; r < 4; ++r)
            wq[ib + (size_t)r * 64] = f2bf(acc[i][j][r] + bv);
        } else if (sec == 1) {
#pragma unroll
          for (int r = 0; r < 4; ++r) {
            const float v = acc[i][j][r] + bv;
            wk[ib + (size_t)r * 64] = f2bf(v);
            pk[ib + (size_t)r * 64] = v;
          }
        } else {
#pragma unroll
          for (int r = 0; r < 4; ++r) {
            const float v = acc[i][j][r] + bv;
            wv[ib + (size_t)r * 64] = f2bf(v);
            pv[ib + (size_t)r * 64] = v;
          }
        }
      }
    }
  } else {
#pragma unroll
    for (int j = 0; j < 4; ++j) {
      const int n = n0 + wn * 64 + j * 16 + lr;
      const float bv = bias[n];
#pragma unroll
      for (int i = 0; i < 4; ++i) {
        const int mb = m0 + wm * 64 + i * 16 + lg * 4;
#pragma unroll
        for (int r = 0; r < 4; ++r)
          of[(size_t)(mb + r) * 1024 + n] = acc[i][j][r] + bv;
      }
    }
  }
}

// ---------------- causal flash attention: uniform-work blocks, barrier-free loop ----------------
// (unchanged from round 13)
__global__ __launch_bounds__(128, 2) void k_attn(const u16* __restrict__ Q,
                                                 const u16* __restrict__ Kp,
                                                 const u16* __restrict__ VT,
                                                 u16* __restrict__ AO) {
  __shared__ __align__(16) u16 Ksh[2][2][4096];  // [wave][buf][64 kpos x 64 d], swizzled

  const int tid = threadIdx.x;
  const int lane = tid & 63, w = tid >> 6;    // w in {0,1}
  const int l31 = lane & 31, hi = lane >> 5;
  const int bid = blockIdx.x;
  const int bh = bid & 31;                    // bh%8 == bid%8 -> XCD-pinned
  const int p = bid >> 5;                     // 0..31
  const int b = bh >> 4, h = bh & 15;
  const size_t hb = (size_t)bh * (2048 * 64);
  const int xr = l31 & 7;                     // read-side swizzle key

  const u16* Kg = Kp + hb + (size_t)(lane >> 3) * 64 + (size_t)(((lane & 7) ^ (lane >> 3)) * 8);
  const u16* Vg = VT + hb + (size_t)l31 * 2048 + hi * 8;

  float* OslB = (float*)&Ksh[0][0][0];   // [32][64] f32, 8 KB (w0 buf0)
  float* ML   = (float*)&Ksh[0][1][0];   // m[64], l[64] (w0 buf1 head)

#define STAGEK(sel, jt)                                       \
  {                                                           \
    u16* kd = &Ksh[w][sel][0];                                \
    const u16* ks = Kg + (size_t)(jt) * 4096;                 \
    gload_lds16(ks,        kd);                               \
    gload_lds16(ks +  512, kd +  512);                        \
    gload_lds16(ks + 1024, kd + 1024);                        \
    gload_lds16(ks + 1536, kd + 1536);                        \
    gload_lds16(ks + 2048, kd + 2048);                        \
    gload_lds16(ks + 2560, kd + 2560);                        \
    gload_lds16(ks + 3072, kd + 3072);                        \
    gload_lds16(ks + 3584, kd + 3584);                        \
  }

#define GL16(dst, ptr, IMM)                                           \
  asm volatile("global_load_dwordx4 %0, %1, off offset:" #IMM         \
               : "=v"(dst) : "v"(ptr));

#define LOADV(jt)                                             \
  {                                                           \
    const u16* vp0 = Vg + (size_t)(jt) * 64;                  \
    const u16* vp1 = vp0 + 65536;                             \
    GL16(vv[0][0], vp0, 0)  GL16(vv[0][1], vp0, 32)           \
    GL16(vv[0][2], vp0, 64) GL16(vv[0][3], vp0, 96)           \
    GL16(vv[1][0], vp1, 0)  GL16(vv[1][1], vp1, 32)           \
    GL16(vv[1][2], vp1, 64) GL16(vv[1][3], vp1, 96)           \
  }

  for (int t = 0; t < 2; ++t) {
    const int qtl = t ? (63 - p) : p;
    const int T = (qtl >> 1) + 1;
    const int mid = (T + 1) >> 1;
    const int lo  = w ? mid : 0;
    const int hiE = w ? T : mid;
    const int qb = qtl * 32;

    const u16* Qp2 = Q + hb + (size_t)(qb + l31) * 64 + hi * 8;
    const bf16x8 qf0 = *(const bf16x8*)(Qp2);
    const bf16x8 qf1 = *(const bf16x8*)(Qp2 + 16);
    const bf16x8 qf2 = *(const bf16x8*)(Qp2 + 32);
    const bf16x8 qf3 = *(const bf16x8*)(Qp2 + 48);

    f32x16 o0 = (f32x16)0.0f, o1 = (f32x16)0.0f;
    float mrun = -1e30f, lrun = 0.0f;

    if (lo < hiE) {
      STAGEK(0, lo)
      int cur = 0;
      for (int jt = lo; jt < hiE; ++jt) {
        const bool hn = (jt + 1 < hiE);
        u32x4 vv[2][4];
        LOADV(jt)                       // V(jt) -> regs (older)
        if (hn) STAGEK(cur ^ 1, jt + 1) // K(jt+1) -> alt buf (younger)
        if (hn) asm volatile("s_waitcnt vmcnt(16)" ::: "memory");
        else    asm volatile("s_waitcnt vmcnt(8)"  ::: "memory");
        __builtin_amdgcn_sched_barrier(0);

        const u16* Kb = &Ksh[w][cur][0];
        bf16x8 kf[2][4];
#pragma unroll
        for (int s = 0; s < 2; ++s)
#pragma unroll
          for (int c = 0; c < 4; ++c)
            kf[s][c] = *(const bf16x8*)&Kb[(s * 32 + l31) * 64 + (((2 * c + hi) ^ xr) * 8)];

        // S^T[kpos][q] = K . Q^T
        f32x16 s0 = (f32x16)0.0f, s1 = (f32x16)0.0f;
        __builtin_amdgcn_s_setprio(1);
        s0 = __builtin_amdgcn_mfma_f32_32x32x16_bf16(kf[0][0], qf0, s0, 0, 0, 0);
        s1 = __builtin_amdgcn_mfma_f32_32x32x16_bf16(kf[1][0], qf0, s1, 0, 0, 0);
        s0 = __builtin_amdgcn_mfma_f32_32x32x16_bf16(kf[0][1], qf1, s0, 0, 0, 0);
        s1 = __builtin_amdgcn_mfma_f32_32x32x16_bf16(kf[1][1], qf1, s1, 0, 0, 0);
        s0 = __builtin_amdgcn_mfma_f32_32x32x16_bf16(kf[0][2], qf2, s0, 0, 0, 0);
        s1 = __builtin_amdgcn_mfma_f32_32x32x16_bf16(kf[1][2], qf2, s1, 0, 0, 0);
        s0 = __builtin_amdgcn_mfma_f32_32x32x16_bf16(kf[0][3], qf3, s0, 0, 0, 0);
        s1 = __builtin_amdgcn_mfma_f32_32x32x16_bf16(kf[1][3], qf3, s1, 0, 0, 0);
        __builtin_amdgcn_s_setprio(0);

        // causal mask (diagonal tile only; qrel = (qtl&1)*32 + l31)
        if (jt == T - 1) {
          const int qrel = (qtl & 1) * 32 + l31;
          const int h4 = hi * 4;
#pragma unroll
          for (int r = 0; r < 16; ++r) {
            const int kp = (r & 3) + ((r >> 2) << 3) + h4;
            s0[r] = (kp <= qrel) ? s0[r] : -1e30f;
            s1[r] = (kp + 32 <= qrel) ? s1[r] : -1e30f;
          }
        }

        // ---- in-register online softmax (lane pair (l31,hi) = one q-row) ----
        float t8[8];
#pragma unroll
        for (int r = 0; r < 8; ++r)
          t8[r] = fmaxf(fmaxf(s0[r], s0[r + 8]), fmaxf(s1[r], s1[r + 8]));
        float tm = fmaxf(fmaxf(fmaxf(t8[0], t8[1]), fmaxf(t8[2], t8[3])),
                         fmaxf(fmaxf(t8[4], t8[5]), fmaxf(t8[6], t8[7])));
        tm = fmaxf(tm, __shfl_xor(tm, 32));
        if (!__all(tm <= mrun)) {
          const float mnew = fmaxf(mrun, tm);
          const float al = fast_exp2((mrun - mnew) * SC);
          mrun = mnew;
          lrun *= al;
#pragma unroll
          for (int r = 0; r < 16; ++r) { o0[r] *= al; o1[r] *= al; }
        }
        const float nb2 = -mrun * SC;
#pragma unroll
        for (int r = 0; r < 16; ++r) {
          s0[r] = fast_exp2(fmaf(s0[r], SC, nb2));
          s1[r] = fast_exp2(fmaf(s1[r], SC, nb2));
        }
        float u8[8];
#pragma unroll
        for (int r = 0; r < 8; ++r)
          u8[r] = (s0[r] + s0[r + 8]) + (s1[r] + s1[r + 8]);
        lrun += ((u8[0] + u8[1]) + (u8[2] + u8[3])) + ((u8[4] + u8[5]) + (u8[6] + u8[7]));

        // ---- pack P to bf16 B-fragments (cvt_pk + permlane32_swap, T12) ----
        bf16x8 pb0, pb1, pb2, pb3;
#define PACK_CHUNK(sv, bb, dst)                                   \
        {                                                         \
          u32 a0 = cvtpk(sv[bb + 0], sv[bb + 1]);                 \
          u32 a1 = cvtpk(sv[bb + 2], sv[bb + 3]);                 \
          u32 a2 = cvtpk(sv[bb + 4], sv[bb + 5]);                 \
          u32 a3 = cvtpk(sv[bb + 6], sv[bb + 7]);                 \
          plswap(a0, a2);                                         \
          plswap(a1, a3);                                         \
          u32x4 fv = {a0, a1, a2, a3};                            \
          dst = __builtin_bit_cast(bf16x8, fv);                   \
        }
        PACK_CHUNK(s0, 0, pb0)
        PACK_CHUNK(s0, 8, pb1)
        PACK_CHUNK(s1, 0, pb2)
        PACK_CHUNK(s1, 8, pb3)
#undef PACK_CHUNK

        if (hn) asm volatile("s_waitcnt vmcnt(8)" ::: "memory");
        else    asm volatile("s_waitcnt vmcnt(0)" ::: "memory");
        __builtin_amdgcn_sched_barrier(0);

        const bf16x8 vf00 = __builtin_bit_cast(bf16x8, vv[0][0]);
        const bf16x8 vf01 = __builtin_bit_cast(bf16x8, vv[0][1]);
        const bf16x8 vf02 = __builtin_bit_cast(bf16x8, vv[0][2]);
        const bf16x8 vf03 = __builtin_bit_cast(bf16x8, vv[0][3]);
        const bf16x8 vf10 = __builtin_bit_cast(bf16x8, vv[1][0]);
        const bf16x8 vf11 = __builtin_bit_cast(bf16x8, vv[1][1]);
        const bf16x8 vf12 = __builtin_bit_cast(bf16x8, vv[1][2]);
        const bf16x8 vf13 = __builtin_bit_cast(bf16x8, vv[1][3]);

        // ---- O^T[d][q] += V^T . P^T ----
        __builtin_amdgcn_s_setprio(1);
        o0 = __builtin_amdgcn_mfma_f32_32x32x16_bf16(vf00, pb0, o0, 0, 0, 0);
        o1 = __builtin_amdgcn_mfma_f32_32x32x16_bf16(vf10, pb0, o1, 0, 0, 0);
        o0 = __builtin_amdgcn_mfma_f32_32x32x16_bf16(vf01, pb1, o0, 0, 0, 0);
        o1 = __builtin_amdgcn_mfma_f32_32x32x16_bf16(vf11, pb1, o1, 0, 0, 0);
        o0 = __builtin_amdgcn_mfma_f32_32x32x16_bf16(vf02, pb2, o0, 0, 0, 0);
        o1 = __builtin_amdgcn_mfma_f32_32x32x16_bf16(vf12, pb2, o1, 0, 0, 0);
        o0 = __builtin_amdgcn_mfma_f32_32x32x16_bf16(vf03, pb3, o0, 0, 0, 0);
        o1 = __builtin_amdgcn_mfma_f32_32x32x16_bf16(vf13, pb3, o1, 0, 0, 0);
        __builtin_amdgcn_s_setprio(0);

        cur ^= 1;
      }
    }

    // ---- cross-wave flash combine (2 barriers; overlay on w0's K area) ----
    __syncthreads();
    if (w == 1) {
#pragma unroll
      for (int r = 0; r < 16; ++r) {
        OslB[r * 64 + lane]        = o0[r];
        OslB[(16 + r) * 64 + lane] = o1[r];
      }
      ML[lane]      = mrun;
      ML[64 + lane] = lrun;
    }
    __syncthreads();
    if (w == 0) {
      const float mB = ML[lane];
      const float lB = ML[64 + lane];
      const float m  = fmaxf(mrun, mB);
      const float al = fast_exp2((mrun - m) * SC);
      const float bt = fast_exp2((mB - m) * SC);
      lrun = lrun * al + lB * bt;
#pragma unroll
      for (int r = 0; r < 16; ++r) {
        o0[r] = o0[r] * al + OslB[r * 64 + lane] * bt;
        o1[r] = o1[r] * al + OslB[(16 + r) * 64 + lane] * bt;
      }

      const float lt = lrun + __shfl_xor(lrun, 32);
      const float inv = 1.0f / lt;
      u16* aorow = AO + (size_t)(b * 2048 + qb + l31) * 1024 + h * 64 + hi * 4;
#pragma unroll
      for (int g2 = 0; g2 < 4; ++g2) {
        u32 w0s = cvtpk(o0[4 * g2 + 0] * inv, o0[4 * g2 + 1] * inv);
        u32 w1s = cvtpk(o0[4 * g2 + 2] * inv, o0[4 * g2 + 3] * inv);
        u32x2 ww = {w0s, w1s};
        *(u32x2*)(aorow + g2 * 8) = ww;
      }
#pragma unroll
      for (int g2 = 0; g2 < 4; ++g2) {
        u32 w0s = cvtpk(o1[4 * g2 + 0] * inv, o1[4 * g2 + 1] * inv);
        u32 w1s = cvtpk(o1[4 * g2 + 2] * inv, o1[4 * g2 + 3] * inv);
        u32x2 ww = {w0s, w1s};
        *(u32x2*)(aorow + 32 + g2 * 8) = ww;
      }
      asm volatile("s_waitcnt lgkmcnt(0)" ::: "memory");
      __builtin_amdgcn_sched_barrier(0);
    }
  }
#undef STAGEK
#undef LOADV
#undef GL16
}

extern "C" void kernel_launch(void* const* d_in, const int* in_sizes, int n_in,
                              void* d_out, int out_size, void* d_ws, size_t ws_size,
                              hipStream_t stream) {
  const float* x      = (const float*)d_in[0];
  const float* w_attn = (const float*)d_in[1];
  const float* b_attn = (const float*)d_in[2];
  const float* w_proj = (const float*)d_in[3];
  const float* b_proj = (const float*)d_in[4];
  float* out = (float*)d_out;

  char* ws = (char*)d_ws;
  u16* x_bf  = (u16*)(ws);                    // [4096][1024] bf16 (8 MB); dead after gemm0
  u16* wat_t = (u16*)(ws + 8388608);          // [3072][1024] bf16   (6 MB)
  u16* wpj_t = (u16*)(ws + 14680064);         // [1024][1024] bf16   (2 MB)
  u16* q_ws  = (u16*)(ws + 16777216);         // [B,H,S,d] bf16      (8 MB)
  u16* k_ws  = (u16*)(ws + 25165824);         // [B,H,S,d] bf16      (8 MB)
  u16* v_ws  = (u16*)(ws + 33554432);         // [B,H,S,d] bf16      (8 MB)
  u16* a_ws  = (u16*)(ws + 41943040);         // [B,S,nx]  bf16      (8 MB)
  u16* vT_ws = (u16*)(ws);                    // [B,H,d,S] bf16, reuses x_bf region

  k_cvt<<<4096, 256, 0, stream>>>(x, x_bf, 4194304);
  k_tcvt<<<dim3(96, 32), dim3(32, 8), 0, stream>>>(w_attn, wat_t, 1024, 3072);
  k_tcvt<<<dim3(32, 32), dim3(32, 8), 0, stream>>>(w_proj, wpj_t, 1024, 1024);

  k_gemm<0><<<dim3(24, 32), 256, 0, stream>>>(x_bf, wat_t, b_attn,
                                              q_ws, k_ws, v_ws,
                                              out + 4194304, out + 8388608, nullptr);

  k_vt<<<dim3(32, 32), 256, 0, stream>>>(v_ws, vT_ws);

  k_attn<<<dim3(1024), 128, 0, stream>>>(q_ws, k_ws, vT_ws, a_ws);

  k_gemm<1><<<dim3(8, 32), 256, 0, stream>>>(a_ws, wpj_t, b_proj,
                                             nullptr, nullptr, nullptr,
                                             nullptr, nullptr, out);
}